// Round 3
// baseline (4879.876 us; speedup 1.0000x reference)
//
#include <hip/hip_runtime.h>
#include <hip/hip_bf16.h>
#include <cstdint>

#define NN   100000
#define EE   1600000
#define EMBD 256
#define DD   128
#define BBB  4096
#define LLL  50
#define NCLS 10

#define FIXS 1048576.0f           /* 2^20 fixed-point scale for spmm accum */
#define INVS (1.0f / 1048576.0f)

__device__ __forceinline__ ushort f2bf(float f) {
  uint32_t u = __float_as_uint(f);
  u += 0x7fffu + ((u >> 16) & 1u);        // round-to-nearest-even
  return (ushort)(u >> 16);
}
__device__ __forceinline__ float bf2f(ushort h) {
  return __uint_as_float(((uint32_t)h) << 16);
}

// ---------------------------------------------------------------------------
// fp32 tiled GEMM: C[M, BN] = A[M, K] @ W[K, BN] (+bias), full-K (no split).
//   AINT: A holds int32 fixed-point (spmm accumulator) -> scale by INVS on load
//   rowidx: optional row gather for A
//   epi: 0 = store f32
//        1 = combine in place: C_int -> float; C = v*n[r] + old*(1-n[r])
//        3 = store bf16 (ushort)
//   remap: out row r -> r + r/50 (packs [*,50] rows into [*,51] layout)
// ---------------------------------------------------------------------------
template<int BM, int BN, int BK, int TM, int TN, int AINT>
__global__ __launch_bounds__(256)
void gemm_f32(const void* __restrict__ Av, int lda,
              const int* __restrict__ rowidx,
              const float* __restrict__ W, int ldw,
              const float* __restrict__ bias,
              void* __restrict__ Cv, int ldc,
              int M, int kchunk,
              int epi, const float* __restrict__ nparam, int remap)
{
  constexpr int TX = BN / TN;
  constexpr int TY = BM / TM;
  static_assert(TX * TY == 256, "thread mapping");
  static_assert(TN == 4, "epilogue uses 4-wide vectors");
  constexpr int AQ = BK / 4;
  static_assert(BM * AQ == 256, "A-tile load mapping");

  __shared__ float As[BK][BM + 4];
  __shared__ float Ws[BK][BN];

  const int tid = threadIdx.x;
  const int tx = tid % TX, ty = tid / TX;
  const int bm0 = blockIdx.x * BM;

  float acc[TM][TN];
#pragma unroll
  for (int i = 0; i < TM; ++i)
#pragma unroll
    for (int j = 0; j < TN; ++j) acc[i][j] = 0.f;

  const int arow_l = tid / AQ;
  const int akq = tid % AQ;
  const int arow_g = bm0 + arow_l;
  long long asrc = -1;
  if (arow_g < M) {
    int ar = rowidx ? rowidx[arow_g] : arow_g;
    asrc = (long long)ar * lda;
  }

  constexpr int WQ4 = BN / 4;
  constexpr int WLOADS = (BK * WQ4) / 256;

  for (int kt = 0; kt < kchunk; kt += BK) {
    float4 av = make_float4(0.f, 0.f, 0.f, 0.f);
    if (asrc >= 0) {
      if (AINT) {
        int4 ai = *(const int4*)((const int*)Av + asrc + kt + (akq << 2));
        av.x = (float)ai.x * INVS; av.y = (float)ai.y * INVS;
        av.z = (float)ai.z * INVS; av.w = (float)ai.w * INVS;
      } else {
        av = *(const float4*)((const float*)Av + asrc + kt + (akq << 2));
      }
    }
    As[(akq << 2) + 0][arow_l] = av.x;
    As[(akq << 2) + 1][arow_l] = av.y;
    As[(akq << 2) + 2][arow_l] = av.z;
    As[(akq << 2) + 3][arow_l] = av.w;
#pragma unroll
    for (int p = 0; p < WLOADS; ++p) {
      int f = tid + p * 256;
      int krow = f / WQ4, c4 = f % WQ4;
      *(float4*)&Ws[krow][c4 << 2] =
          *(const float4*)(W + (long long)(kt + krow) * ldw + (c4 << 2));
    }
    __syncthreads();
#pragma unroll
    for (int kk = 0; kk < BK; ++kk) {
      float a[TM], b[TN];
#pragma unroll
      for (int i = 0; i < TM; i += 4)
        *(float4*)&a[i] = *(const float4*)&As[kk][ty * TM + i];
      *(float4*)&b[0] = *(const float4*)&Ws[kk][tx * TN];
#pragma unroll
      for (int i = 0; i < TM; ++i)
#pragma unroll
        for (int j = 0; j < TN; ++j)
          acc[i][j] = fmaf(a[i], b[j], acc[i][j]);
    }
    __syncthreads();
  }

#pragma unroll
  for (int i = 0; i < TM; ++i) {
    int r = bm0 + ty * TM + i;
    if (r >= M) continue;
    int rr = remap ? (r + r / 50) : r;
    float4 v = make_float4(acc[i][0], acc[i][1], acc[i][2], acc[i][3]);
    if (bias != nullptr) {
      v.x += bias[tx * TN + 0]; v.y += bias[tx * TN + 1];
      v.z += bias[tx * TN + 2]; v.w += bias[tx * TN + 3];
    }
    if (epi == 0) {
      *(float4*)((float*)Cv + (long long)rr * ldc + tx * TN) = v;
    } else if (epi == 1) {
      float nv = nparam[r];
      int* cp = (int*)Cv + (long long)rr * ldc + tx * TN;
      int4 oi = *(const int4*)cp;
      v.x = v.x * nv + ((float)oi.x * INVS) * (1.f - nv);
      v.y = v.y * nv + ((float)oi.y * INVS) * (1.f - nv);
      v.z = v.z * nv + ((float)oi.z * INVS) * (1.f - nv);
      v.w = v.w * nv + ((float)oi.w * INVS) * (1.f - nv);
      int4 wi;
      wi.x = __float_as_int(v.x); wi.y = __float_as_int(v.y);
      wi.z = __float_as_int(v.z); wi.w = __float_as_int(v.w);
      *(int4*)cp = wi;
    } else {                       // epi == 3: bf16 store
      ushort* cp = (ushort*)Cv + (long long)rr * ldc + tx * TN;
      ushort4 w4;
      w4.x = f2bf(v.x); w4.y = f2bf(v.y); w4.z = f2bf(v.z); w4.w = f2bf(v.w);
      *(ushort4*)cp = w4;
    }
  }
}

// ---------------------------------------------------------------------------
// SPMM scatter: X_fix[dst] += round(H[src]*w * 2^20)  (int32 atomics =>
// order-independent, bit-deterministic across replays)
// ---------------------------------------------------------------------------
template<int HBF16>
__global__ __launch_bounds__(256)
void spmm_kernel(const int* __restrict__ src, const int* __restrict__ dst,
                 const float* __restrict__ w,
                 const void* __restrict__ H, int* __restrict__ X, int E)
{
  int e = blockIdx.x * 8 + (threadIdx.x >> 5);
  if (e >= E) return;
  int lane = threadIdx.x & 31;
  int s = src[e], d = dst[e];
  float we = w[e];
  float4 v;
  if (HBF16) {
    ushort4 hv = *((const ushort4*)H + (size_t)s * 32 + lane);
    v.x = bf2f(hv.x); v.y = bf2f(hv.y); v.z = bf2f(hv.z); v.w = bf2f(hv.w);
  } else {
    v = *((const float4*)H + (size_t)s * 32 + lane);
  }
  int* xp = X + (size_t)d * DD + (lane << 2);
  atomicAdd(xp + 0, __float2int_rn(v.x * we * FIXS));
  atomicAdd(xp + 1, __float2int_rn(v.y * we * FIXS));
  atomicAdd(xp + 2, __float2int_rn(v.z * we * FIXS));
  atomicAdd(xp + 3, __float2int_rn(v.w * we * FIXS));
}

// ---------------------------------------------------------------------------
// Row 50 of each batch's Y block: sum of rows 0..49 minus 49*bias2
// ---------------------------------------------------------------------------
__global__ __launch_bounds__(256)
void sumrow_kernel(float* __restrict__ Y, const float* __restrict__ bias2, int Bc)
{
  int t = blockIdx.x * 256 + threadIdx.x;
  int b = t >> 4, j4 = t & 15;
  if (b >= Bc) return;
  const float4* yb = (const float4*)(Y + (size_t)b * 51 * 64);
  float4 s = make_float4(0.f, 0.f, 0.f, 0.f);
  for (int l = 0; l < 50; ++l) {
    float4 v = yb[l * 16 + j4];
    s.x += v.x; s.y += v.y; s.z += v.z; s.w += v.w;
  }
  float4 bb = *(const float4*)(bias2 + (j4 << 2));
  s.x -= 49.f * bb.x; s.y -= 49.f * bb.y;
  s.z -= 49.f * bb.z; s.w -= 49.f * bb.w;
  *(float4*)(Y + (size_t)b * 51 * 64 + 50 * 64 + (j4 << 2)) = s;
}

// ---------------------------------------------------------------------------
// Classifier + argmax (first-max tie-break, matches jnp.argmax).
// ---------------------------------------------------------------------------
__global__ __launch_bounds__(256)
void cls_kernel(const float* __restrict__ sel, const float* __restrict__ Wc,
                const float* __restrict__ bc, float* __restrict__ outIdx)
{
  int wv = threadIdx.x >> 6;
  int lane = threadIdx.x & 63;
  int b = blockIdx.x * 4 + wv;
  if (b >= BBB) return;
  float logit = -1e30f;
  if (lane < NCLS) {
    float s = bc[lane];
    const float* sr = sel + (size_t)b * DD;
    for (int d = 0; d < DD; ++d) s = fmaf(sr[d], Wc[d * NCLS + lane], s);
    logit = s;
  }
  float best = -1e30f; int bi = 0;
  for (int c = 0; c < NCLS; ++c) {
    float v = __shfl(logit, c, 64);
    if (v > best) { best = v; bi = c; }
  }
  if (lane == 0) outIdx[b] = (float)bi;
}

// ---------------------------------------------------------------------------
extern "C" void kernel_launch(void* const* d_in, const int* in_sizes, int n_in,
                              void* d_out, int out_size, void* d_ws, size_t ws_size,
                              hipStream_t stream)
{
  const float* A1    = (const float*)d_in[0];
  const int*   esrc  = (const int*)d_in[1];
  const int*   edst  = (const int*)d_in[2];
  const float* ew    = (const float*)d_in[3];
  const int*   bidx  = (const int*)d_in[4];   // [B,1,L] == [B*L]
  const float* wgc1  = (const float*)d_in[5];
  const float* bgc1  = (const float*)d_in[6];
  const float* wgc2  = (const float*)d_in[7];
  const float* bgc2  = (const float*)d_in[8];
  const float* npar  = (const float*)d_in[9];
  const float* lin1  = (const float*)d_in[10];
  const float* lin1b = (const float*)d_in[11];
  const float* w2    = (const float*)d_in[12];
  const float* b2    = (const float*)d_in[13];
  const float* l1w   = (const float*)d_in[14];
  const float* l1b   = (const float*)d_in[15];
  const float* clsw  = (const float*)d_in[16];
  const float* clsb  = (const float*)d_in[17];

  float* out = (float*)d_out;
  const size_t NDf = (size_t)NN * DD;                       // 12.8M elems
  const size_t Yf  = (size_t)BBB * 51 * 64;                 // 13.37M elems

  // ws budget gate: full fp32 path needs (NDf + Yf)*4 = 104.7 MB.
  const bool roomy = ws_size >= (NDf + Yf) * 4;
  const int  G  = roomy ? 1 : 4;                            // Y batch chunks
  const int  Bc = BBB / G;

  float* R1   = (float*)d_ws;                 // x-accum: int32 fixed -> float
  void*  R0   = (void*)(R1 + NDf);            // h (f32 or bf16); Y overlays it
  float* Ybuf = (float*)R0;

  dim3 blk(256);
  const int gN = (NN + 63) / 64;              // 1563

  // h1 = A1 @ w_gc1 + b_gc1 -> R0
  hipLaunchKernelGGL((gemm_f32<64,128,16,8,4,0>), dim3(gN), blk, 0, stream,
      A1, EMBD, (const int*)nullptr, wgc1, DD, bgc1, R0, DD,
      NN, EMBD, roomy ? 0 : 3, (const float*)nullptr, 0);

  // spmm1: R1(int) += round(w * h1[src] * S) scattered to dst
  hipMemsetAsync(R1, 0, NDf * 4, stream);
  if (roomy)
    hipLaunchKernelGGL((spmm_kernel<0>), dim3(EE / 8), blk, 0, stream,
        esrc, edst, ew, (const void*)R0, (int*)R1, EE);
  else
    hipLaunchKernelGGL((spmm_kernel<1>), dim3(EE / 8), blk, 0, stream,
        esrc, edst, ew, (const void*)R0, (int*)R1, EE);

  // x1 = (A1 @ Lin1 + b)*n + x1_fix*invS*(1-n) -> R1 (int -> float in place)
  hipLaunchKernelGGL((gemm_f32<64,128,16,8,4,0>), dim3(gN), blk, 0, stream,
      A1, EMBD, (const int*)nullptr, lin1, DD, lin1b, R1, DD,
      NN, EMBD, 1, npar, 0);

  // h2 = x1 @ w_gc2 + b_gc2 -> R0
  hipLaunchKernelGGL((gemm_f32<64,128,16,8,4,0>), dim3(gN), blk, 0, stream,
      R1, DD, (const int*)nullptr, wgc2, DD, bgc2, R0, DD,
      NN, DD, roomy ? 0 : 3, (const float*)nullptr, 0);

  // spmm2 -> R1 (int fixed-point)
  hipMemsetAsync(R1, 0, NDf * 4, stream);
  if (roomy)
    hipLaunchKernelGGL((spmm_kernel<0>), dim3(EE / 8), blk, 0, stream,
        esrc, edst, ew, (const void*)R0, (int*)R1, EE);
  else
    hipLaunchKernelGGL((spmm_kernel<1>), dim3(EE / 8), blk, 0, stream,
        esrc, edst, ew, (const void*)R0, (int*)R1, EE);

  // Per batch-chunk: gather-einsum -> Y, sum-row, final GEMM (no atomics).
  for (int c = 0; c < G; ++c) {
    const int* bidx_c = bidx + (size_t)c * Bc * LLL;
    const int Mc = Bc * LLL;
    // Y[b,l,:] = x2[bidx[b,l]] @ weight2 + bias2  (rows remapped to [*,51,64])
    hipLaunchKernelGGL((gemm_f32<64,64,16,4,4,1>), dim3(Mc / 64), blk, 0, stream,
        (const void*)R1, DD, bidx_c, w2, 64, b2, (void*)Ybuf, 64,
        Mc, DD, 0, (const float*)nullptr, 1);
    // Y[b,50,:] = sum_l Y[b,l,:] - 49*bias2
    hipLaunchKernelGGL(sumrow_kernel, dim3(Bc / 16), blk, 0, stream,
        Ybuf, b2, Bc);
    // sel rows [c*Bc, (c+1)*Bc) = Y.reshape(Bc,3264) @ lin1_w + lin1_b
    for (int h = 0; h < 2; ++h) {
      const int n0 = h * 64;
      hipLaunchKernelGGL((gemm_f32<64,64,16,4,4,0>), dim3(Bc / 64), blk, 0, stream,
          (const void*)Ybuf, 51 * 64, (const int*)nullptr, l1w + n0, DD,
          l1b + n0, (void*)(out + BBB + (size_t)c * Bc * DD + n0), DD,
          Bc, (LLL + 1) * 64, 0, (const float*)nullptr, 0);
    }
  }

  // argmax(sel @ classifier + bias) -> out[0:B] (as float)
  hipLaunchKernelGGL(cls_kernel, dim3(BBB / 4), blk, 0, stream,
      out + BBB, clsw, clsb, out);
}

// Round 5
// 819.546 us; speedup vs baseline: 5.9544x; 5.9544x over previous
//
#include <hip/hip_runtime.h>
#include <hip/hip_bf16.h>
#include <cstdint>

#define NN   100000
#define EE   1600000
#define EMBD 256
#define DD   128
#define BBB  4096
#define LLL  50
#define NCLS 10

#define FIXS 1048576.0f           /* 2^20 fixed-point scale for spmm accum */
#define INVS (1.0f / 1048576.0f)

// ---------------------------------------------------------------------------
// fp32 tiled GEMM: C[M, BN(grid.y slices)] = A[M,K] @ W[K,*] (+bias)
//  bidxg!=null: gather-A mode (final GEMM): A(r,k) =
//      k<3200 ? Z[bidx[r*50 + k/64]*64 + k%64] : S[r*64 + k%64]
//  epi: 0 = store f32
//       1 = combine in place: C_int(U) -> C = v*n[r] + U*INVS*(1-n[r]) + b2c[col]
// ---------------------------------------------------------------------------
template<int BM, int BN, int BK, int TM, int TN>
__global__ __launch_bounds__(256)
void gemm_f32(const void* __restrict__ Av, int lda,
              const float* __restrict__ W, int ldw,
              const float* __restrict__ bias,
              void* __restrict__ Cv, int ldc,
              int M, int kchunk, int epi,
              const float* __restrict__ nparam,
              const float* __restrict__ b2c,
              const int* __restrict__ bidxg,
              const float* __restrict__ Sg)
{
  constexpr int TX = BN / TN;
  constexpr int TY = BM / TM;
  static_assert(TX * TY == 256, "thread mapping");
  static_assert(TN == 4, "epilogue uses 4-wide vectors");
  constexpr int AQ = BK / 4;
  static_assert(BM * AQ == 256, "A-tile load mapping");

  __shared__ float As[BK][BM + 4];
  __shared__ float Ws[BK][BN];

  const int tid = threadIdx.x;
  const int tx = tid % TX, ty = tid / TX;
  const int bm0 = blockIdx.x * BM;
  const int bn0 = blockIdx.y * BN;
  W += bn0;
  const float* biasp = bias ? bias + bn0 : nullptr;

  float acc[TM][TN];
#pragma unroll
  for (int i = 0; i < TM; ++i)
#pragma unroll
    for (int j = 0; j < TN; ++j) acc[i][j] = 0.f;

  const int arow_l = tid / AQ;
  const int akq = tid % AQ;
  const int arow_g = bm0 + arow_l;
  const bool arow_ok = arow_g < M;
  const long long asrc = (long long)arow_g * lda;

  constexpr int WQ4 = BN / 4;
  constexpr int WLOADS = (BK * WQ4) / 256;

  for (int kt = 0; kt < kchunk; kt += BK) {
    float4 av = make_float4(0.f, 0.f, 0.f, 0.f);
    if (arow_ok) {
      if (bidxg) {
        int k = kt + (akq << 2);
        int l = k >> 6, j = k & 63;
        const float* ap = (l < LLL)
            ? ((const float*)Av + (size_t)bidxg[arow_g * LLL + l] * 64 + j)
            : (Sg + (size_t)arow_g * 64 + j);
        av = *(const float4*)ap;
      } else {
        av = *(const float4*)((const float*)Av + asrc + kt + (akq << 2));
      }
    }
    As[(akq << 2) + 0][arow_l] = av.x;
    As[(akq << 2) + 1][arow_l] = av.y;
    As[(akq << 2) + 2][arow_l] = av.z;
    As[(akq << 2) + 3][arow_l] = av.w;
#pragma unroll
    for (int p = 0; p < WLOADS; ++p) {
      int f = tid + p * 256;
      int krow = f / WQ4, c4 = f % WQ4;
      *(float4*)&Ws[krow][c4 << 2] =
          *(const float4*)(W + (long long)(kt + krow) * ldw + (c4 << 2));
    }
    __syncthreads();
#pragma unroll
    for (int kk = 0; kk < BK; ++kk) {
      float a[TM], b[TN];
      if constexpr (TM % 4 == 0) {
#pragma unroll
        for (int i = 0; i < TM; i += 4)
          *(float4*)&a[i] = *(const float4*)&As[kk][ty * TM + i];
      } else {
#pragma unroll
        for (int i = 0; i < TM; ++i) a[i] = As[kk][ty * TM + i];
      }
      *(float4*)&b[0] = *(const float4*)&Ws[kk][tx * TN];
#pragma unroll
      for (int i = 0; i < TM; ++i)
#pragma unroll
        for (int j = 0; j < TN; ++j)
          acc[i][j] = fmaf(a[i], b[j], acc[i][j]);
    }
    __syncthreads();
  }

#pragma unroll
  for (int i = 0; i < TM; ++i) {
    int r = bm0 + ty * TM + i;
    if (r >= M) continue;
    float4 v = make_float4(acc[i][0], acc[i][1], acc[i][2], acc[i][3]);
    if (biasp != nullptr) {
      v.x += biasp[tx * TN + 0]; v.y += biasp[tx * TN + 1];
      v.z += biasp[tx * TN + 2]; v.w += biasp[tx * TN + 3];
    }
    const long long coff = (long long)r * ldc + bn0 + tx * TN;
    if (epi == 0) {
      *(float4*)((float*)Cv + coff) = v;
    } else {                      // epi == 1: combine with U (int fixed) + b2c
      float nv = nparam[r];
      int* cp = (int*)Cv + coff;
      int4 oi = *(const int4*)cp;
      const int c0 = bn0 + tx * TN;
      v.x = v.x * nv + ((float)oi.x * INVS) * (1.f - nv) + b2c[c0 + 0];
      v.y = v.y * nv + ((float)oi.y * INVS) * (1.f - nv) + b2c[c0 + 1];
      v.z = v.z * nv + ((float)oi.z * INVS) * (1.f - nv) + b2c[c0 + 2];
      v.w = v.w * nv + ((float)oi.w * INVS) * (1.f - nv) + b2c[c0 + 3];
      int4 wi;
      wi.x = __float_as_int(v.x); wi.y = __float_as_int(v.y);
      wi.z = __float_as_int(v.z); wi.w = __float_as_int(v.w);
      *(int4*)cp = wi;
    }
  }
}

// ---------------------------------------------------------------------------
// Tiny dense GEMM for weight fusion: C[M,N] = A[M,K] @ B[K,N]
// ---------------------------------------------------------------------------
__global__ __launch_bounds__(256)
void wmm(const float* __restrict__ A, const float* __restrict__ B,
         float* __restrict__ C, int M, int K, int N)
{
  int t = blockIdx.x * 256 + threadIdx.x;
  if (t >= M * N) return;
  int m = t / N, n = t % N;
  float s = 0.f;
  for (int k = 0; k < K; ++k) s = fmaf(A[m * K + k], B[k * N + n], s);
  C[t] = s;
}

// ---------------------------------------------------------------------------
// CSR build: histogram -> 3-pass exclusive scan -> scatter permutation
// ---------------------------------------------------------------------------
__global__ __launch_bounds__(256)
void hist_k(const int* __restrict__ dst, int* __restrict__ cur)
{
  int e = blockIdx.x * 256 + threadIdx.x;
  if (e < EE) atomicAdd(&cur[dst[e]], 1);
}

__global__ __launch_bounds__(256)
void scan1_k(const int* __restrict__ cnt, int* __restrict__ rp1,
             int* __restrict__ part, int n)
{
  __shared__ int s[256];
  int t = threadIdx.x;
  int base = blockIdx.x * 1024 + t * 4;
  int a0 = (base + 0 < n) ? cnt[base + 0] : 0;
  int a1 = (base + 1 < n) ? cnt[base + 1] : 0;
  int a2 = (base + 2 < n) ? cnt[base + 2] : 0;
  int a3 = (base + 3 < n) ? cnt[base + 3] : 0;
  s[t] = a0 + a1 + a2 + a3;
  __syncthreads();
  for (int off = 1; off < 256; off <<= 1) {
    int v = (t >= off) ? s[t - off] : 0;
    __syncthreads();
    s[t] += v;
    __syncthreads();
  }
  int pre = t ? s[t - 1] : 0;
  int r0 = pre + a0, r1 = r0 + a1, r2 = r1 + a2, r3 = r2 + a3;
  if (base + 0 < n) rp1[base + 0] = r0;
  if (base + 1 < n) rp1[base + 1] = r1;
  if (base + 2 < n) rp1[base + 2] = r2;
  if (base + 3 < n) rp1[base + 3] = r3;
  if (t == 255) part[blockIdx.x] = s[255];
}

__global__ __launch_bounds__(256)
void scan2_k(int* __restrict__ part, int nb)
{
  __shared__ int s[256];
  int t = threadIdx.x;
  int v = (t < nb) ? part[t] : 0;
  s[t] = v;
  __syncthreads();
  for (int off = 1; off < 256; off <<= 1) {
    int u = (t >= off) ? s[t - off] : 0;
    __syncthreads();
    s[t] += u;
    __syncthreads();
  }
  if (t < nb) part[t] = s[t] - v;     // exclusive
}

__global__ __launch_bounds__(256)
void scan3_k(int* __restrict__ rp, const int* __restrict__ part, int n)
{
  int i = blockIdx.x * 256 + threadIdx.x;
  if (i == 0) rp[0] = 0;
  if (i < n) rp[1 + i] += part[i >> 10];
}

__global__ __launch_bounds__(256)
void scatter_k(const int* __restrict__ dst, const int* __restrict__ rp,
               int* __restrict__ cur, int* __restrict__ perm)
{
  int e = blockIdx.x * 256 + threadIdx.x;
  if (e >= EE) return;
  int d = dst[e];
  int pos = rp[d] + atomicAdd(&cur[d], 1);
  perm[pos] = e;
}

// ---------------------------------------------------------------------------
// CSR spmm on 64-wide f32 rows: one wave per dst node, lane owns one column.
// 64 lanes prefetch <=64 edges' (src,w); inner loop 8-way load-batched.
// Accumulates round(v*w*2^20) in int registers -> bit-deterministic.
// OUTF32: out = acc*INVS + bias[lane] (f32); else raw int.
// ---------------------------------------------------------------------------
template<int OUTF32>
__global__ __launch_bounds__(256)
void spmm64(const int* __restrict__ rp, const int* __restrict__ perm,
            const int* __restrict__ esrc, const float* __restrict__ ew,
            const float* __restrict__ Gf, void* __restrict__ xout,
            const float* __restrict__ bias)
{
  int widx = blockIdx.x * 4 + (threadIdx.x >> 6);
  if (widx >= NN) return;
  int lane = threadIdx.x & 63;
  int e0 = rp[widx], e1 = rp[widx + 1];
  int acc = 0;
  for (int g0 = e0; g0 < e1; g0 += 64) {
    int ee = g0 + lane;
    int s = 0; float w = 0.f;
    if (ee < e1) {
      int p = perm[ee];
      s = esrc[p];
      w = ew[p];
    }
    int m = e1 - g0; if (m > 64) m = 64;
    int j = 0;
    for (; j + 8 <= m; j += 8) {
      float gv[8], wv[8];
#pragma unroll
      for (int u = 0; u < 8; ++u) {
        int sj = __shfl(s, j + u, 64);
        wv[u] = __shfl(w, j + u, 64);
        gv[u] = Gf[(size_t)sj * 64 + lane];
      }
#pragma unroll
      for (int u = 0; u < 8; ++u)
        acc += __float2int_rn(gv[u] * wv[u] * FIXS);
    }
    for (; j < m; ++j) {
      int sj = __shfl(s, j, 64);
      float wj = __shfl(w, j, 64);
      acc += __float2int_rn(Gf[(size_t)sj * 64 + lane] * wj * FIXS);
    }
  }
  if (OUTF32)
    ((float*)xout)[(size_t)widx * 64 + lane] = (float)acc * INVS + bias[lane];
  else
    ((int*)xout)[(size_t)widx * 64 + lane] = acc;
}

// ---------------------------------------------------------------------------
// S[b,:] = sum_l Z[bidx[b,l],:] - 49*b2   (Z rows already carry +b2 each)
// ---------------------------------------------------------------------------
__global__ __launch_bounds__(256)
void sumS_k(const float* __restrict__ Z, const int* __restrict__ bidx,
            const float* __restrict__ b2, float* __restrict__ S)
{
  int wv = threadIdx.x >> 6;
  int lane = threadIdx.x & 63;
  int b = blockIdx.x * 4 + wv;
  if (b >= BBB) return;
  const int* bi = bidx + (size_t)b * LLL;
  float s = 0.f;
  for (int l = 0; l < LLL; ++l)
    s += Z[(size_t)bi[l] * 64 + lane];
  S[(size_t)b * 64 + lane] = s - 49.f * b2[lane];
}

// ---------------------------------------------------------------------------
// Classifier + argmax (first-max tie-break, matches jnp.argmax).
// ---------------------------------------------------------------------------
__global__ __launch_bounds__(256)
void cls_k(const float* __restrict__ sel, const float* __restrict__ Wc,
           const float* __restrict__ bc, float* __restrict__ outIdx)
{
  int wv = threadIdx.x >> 6;
  int lane = threadIdx.x & 63;
  int b = blockIdx.x * 4 + wv;
  if (b >= BBB) return;
  float logit = -1e30f;
  if (lane < NCLS) {
    float s = bc[lane];
    const float* sr = sel + (size_t)b * DD;
    for (int d = 0; d < DD; ++d) s = fmaf(sr[d], Wc[d * NCLS + lane], s);
    logit = s;
  }
  float best = -1e30f; int bi = 0;
  for (int c = 0; c < NCLS; ++c) {
    float v = __shfl(logit, c, 64);
    if (v > best) { best = v; bi = c; }
  }
  if (lane == 0) outIdx[b] = (float)bi;
}

// ---------------------------------------------------------------------------
extern "C" void kernel_launch(void* const* d_in, const int* in_sizes, int n_in,
                              void* d_out, int out_size, void* d_ws, size_t ws_size,
                              hipStream_t stream)
{
  const float* A1    = (const float*)d_in[0];
  const int*   esrc  = (const int*)d_in[1];
  const int*   edst  = (const int*)d_in[2];
  const float* ew    = (const float*)d_in[3];
  const int*   bidx  = (const int*)d_in[4];   // [B,1,L] == [B*L]
  const float* wgc1  = (const float*)d_in[5];
  const float* bgc1  = (const float*)d_in[6];
  const float* wgc2  = (const float*)d_in[7];
  const float* bgc2  = (const float*)d_in[8];
  const float* npar  = (const float*)d_in[9];
  const float* lin1  = (const float*)d_in[10];
  const float* lin1b = (const float*)d_in[11];
  const float* w2    = (const float*)d_in[12];
  const float* b2    = (const float*)d_in[13];
  const float* l1w   = (const float*)d_in[14];
  const float* l1b   = (const float*)d_in[15];
  const float* clsw  = (const float*)d_in[16];
  const float* clsb  = (const float*)d_in[17];

  float* out = (float*)d_out;
  float* sel = out + BBB;

  // workspace layout (peak 85.5 MB; proven floor from round 1 is 104.67 MB)
  uint8_t* ws   = (uint8_t*)d_ws;
  float*   Q    = (float*)(ws);                 // 25.6 MB [N,64]
  void*    UG   = (void*)  (ws + 25600000);     // 25.6 MB U(int) -> G(f32)
  float*   Z    = (float*)(ws + 51200000);      // 25.6 MB [N,64]
  int*     perm = (int*)  (ws + 76800000);      //  6.4 MB
  int*     rp   = (int*)  (ws + 83200000);      //  0.4 MB (N+1)
  int*     cur  = (int*)  (ws + 83600016);      //  0.4 MB
  int*     part = (int*)  (ws + 84000016);      //  512 B
  float*   S    = (float*)(ws + 84000528);      //  1.0 MB [B,64]
  float*   T1   = (float*)(ws + 85049104);      // 128 KB [256,128]
  float*   T2   = (float*)(ws + 85180176);      // 128 KB
  float*   Wa   = (float*)(ws + 85311248);      //  64 KB [256,64]
  float*   Wb   = (float*)(ws + 85376784);      //  64 KB
  float*   ta   = (float*)(ws + 85442320);      // 512 B [1,128]
  float*   tb   = (float*)(ws + 85442832);      // 512 B
  float*   ba   = (float*)(ws + 85443344);      // 256 B [1,64]
  float*   bb   = (float*)(ws + 85443600);      // 256 B
  float*   bc   = (float*)(ws + 85443856);      // 256 B

  dim3 blk(256);

  // ---- weight fusion (exact fp32, tiny) ----
  hipLaunchKernelGGL(wmm, dim3(128), blk, 0, stream, wgc1, wgc2, T1, EMBD, DD, DD);
  hipLaunchKernelGGL(wmm, dim3(64),  blk, 0, stream, T1, w2, Wa, EMBD, DD, 64);
  hipLaunchKernelGGL(wmm, dim3(1),   blk, 0, stream, bgc1, wgc2, ta, 1, DD, DD);
  hipLaunchKernelGGL(wmm, dim3(1),   blk, 0, stream, ta, w2, ba, 1, DD, 64);
  hipLaunchKernelGGL(wmm, dim3(128), blk, 0, stream, lin1, wgc2, T2, EMBD, DD, DD);
  hipLaunchKernelGGL(wmm, dim3(64),  blk, 0, stream, T2, w2, Wb, EMBD, DD, 64);
  hipLaunchKernelGGL(wmm, dim3(1),   blk, 0, stream, lin1b, wgc2, tb, 1, DD, DD);
  hipLaunchKernelGGL(wmm, dim3(1),   blk, 0, stream, tb, w2, bb, 1, DD, 64);
  hipLaunchKernelGGL(wmm, dim3(1),   blk, 0, stream, bgc2, w2, bc, 1, DD, 64);

  // ---- CSR build (shared by both spmms) ----
  hipMemsetAsync(cur, 0, NN * 4, stream);
  hipLaunchKernelGGL(hist_k, dim3(EE / 256), blk, 0, stream, edst, cur);
  hipLaunchKernelGGL(scan1_k, dim3(98), blk, 0, stream, cur, rp + 1, part, NN);
  hipLaunchKernelGGL(scan2_k, dim3(1), blk, 0, stream, part, 98);
  hipLaunchKernelGGL(scan3_k, dim3(391), blk, 0, stream, rp, part, NN);
  hipMemsetAsync(cur, 0, NN * 4, stream);
  hipLaunchKernelGGL(scatter_k, dim3(EE / 256), blk, 0, stream, edst, rp, cur, perm);

  // ---- Q = A1 @ Wa + ba  [N,64] ----
  hipLaunchKernelGGL((gemm_f32<64,64,16,4,4>), dim3(1563), blk, 0, stream,
      (const void*)A1, EMBD, Wa, 64, ba, (void*)Q, 64,
      NN, EMBD, 0, (const float*)nullptr, (const float*)nullptr,
      (const int*)nullptr, (const float*)nullptr);

  // ---- U = spmm(Q) (int fixed) -> UG ----
  hipLaunchKernelGGL((spmm64<0>), dim3(NN / 4), blk, 0, stream,
      rp, perm, esrc, ew, Q, UG, (const float*)nullptr);

  // ---- G = n*(A1@Wb + bb) + (1-n)*U + bc  (in place over UG) ----
  hipLaunchKernelGGL((gemm_f32<64,64,16,4,4>), dim3(1563), blk, 0, stream,
      (const void*)A1, EMBD, Wb, 64, bb, UG, 64,
      NN, EMBD, 1, npar, bc, (const int*)nullptr, (const float*)nullptr);

  // ---- Z = spmm(G) + b2  [N,64] f32 ----
  hipLaunchKernelGGL((spmm64<1>), dim3(NN / 4), blk, 0, stream,
      rp, perm, esrc, ew, (const float*)UG, (void*)Z, b2);

  // ---- S[b] = sum_l Z[bidx[b,l]] - 49*b2 ----
  hipLaunchKernelGGL(sumS_k, dim3(BBB / 4), blk, 0, stream, Z, bidx, b2, S);

  // ---- sel = [gather(Z) | S].reshape(B,3264) @ l1w + l1b ----
  hipLaunchKernelGGL((gemm_f32<32,64,32,2,4>), dim3(BBB / 32, 2), blk, 0, stream,
      (const void*)Z, 64, l1w, DD, l1b, (void*)sel, DD,
      BBB, (LLL + 1) * 64, 0, (const float*)nullptr, (const float*)nullptr,
      bidx, S);

  // ---- argmax(sel @ classifier + bias) -> out[0:B] ----
  hipLaunchKernelGGL(cls_k, dim3(BBB / 4), blk, 0, stream, sel, clsw, clsb, out);
}

// Round 6
// 601.182 us; speedup vs baseline: 8.1171x; 1.3632x over previous
//
#include <hip/hip_runtime.h>
#include <cstdint>

#define NN   100000
#define EE   1600000
#define EMBD 256
#define DD   128
#define BBB  4096
#define LLL  50
#define NCLS 10

#define FIXS 1048576.0f           /* 2^20 fixed-point scale for spmm accum */
#define INVS (1.0f / 1048576.0f)

// ---------------------------------------------------------------------------
// fp32 tiled GEMM: C[M, BN(grid.y)] = A[M,K] @ W[K,*] (+bias)
//  grid.z splits K into chunks of kper; chunk z writes C + z*M*ldc.
//  bidxg!=null: gather-A mode: A(r,k) =
//      k<3200 ? Z[bidx[r*50 + k/64]*64 + k%64] : S[r*64 + k%64]
// ---------------------------------------------------------------------------
template<int BM, int BN, int BK, int TM, int TN>
__global__ __launch_bounds__(256)
void gemm_f32(const float* __restrict__ Av, int lda,
              const float* __restrict__ W, int ldw,
              const float* __restrict__ bias,
              float* __restrict__ Cv, int ldc,
              int M, int ktot, int kper,
              const int* __restrict__ bidxg,
              const float* __restrict__ Sg)
{
  constexpr int TX = BN / TN;
  constexpr int TY = BM / TM;
  static_assert(TX * TY == 256, "thread mapping");
  static_assert(TN == 4, "epilogue uses 4-wide vectors");
  constexpr int AQ = BK / 4;
  static_assert(BM * AQ == 256, "A-tile load mapping");

  __shared__ float As[BK][BM + 4];
  __shared__ float Ws[BK][BN];

  const int tid = threadIdx.x;
  const int tx = tid % TX, ty = tid / TX;
  const int bm0 = blockIdx.x * BM;
  const int bn0 = blockIdx.y * BN;
  const int z = blockIdx.z;
  const int koff = z * kper;
  int kc = ktot - koff; if (kc > kper) kc = kper;
  W += bn0 + (size_t)koff * ldw;
  Cv += (size_t)z * (size_t)M * ldc;
  const float* biasp = bias ? bias + bn0 : nullptr;

  float acc[TM][TN];
#pragma unroll
  for (int i = 0; i < TM; ++i)
#pragma unroll
    for (int j = 0; j < TN; ++j) acc[i][j] = 0.f;

  const int arow_l = tid / AQ;
  const int akq = tid % AQ;
  const int arow_g = bm0 + arow_l;
  const bool arow_ok = arow_g < M;
  const long long asrc = (long long)arow_g * lda + koff;

  constexpr int WQ4 = BN / 4;
  constexpr int WLOADS = (BK * WQ4) / 256;

  for (int kt = 0; kt < kc; kt += BK) {
    float4 av = make_float4(0.f, 0.f, 0.f, 0.f);
    if (arow_ok) {
      if (bidxg) {
        int k = koff + kt + (akq << 2);
        int l = k >> 6, j = k & 63;
        const float* ap = (l < LLL)
            ? (Av + (size_t)bidxg[arow_g * LLL + l] * 64 + j)
            : (Sg + (size_t)arow_g * 64 + j);
        av = *(const float4*)ap;
      } else {
        av = *(const float4*)(Av + asrc + kt + (akq << 2));
      }
    }
    As[(akq << 2) + 0][arow_l] = av.x;
    As[(akq << 2) + 1][arow_l] = av.y;
    As[(akq << 2) + 2][arow_l] = av.z;
    As[(akq << 2) + 3][arow_l] = av.w;
#pragma unroll
    for (int p = 0; p < WLOADS; ++p) {
      int f = tid + p * 256;
      int krow = f / WQ4, c4 = f % WQ4;
      *(float4*)&Ws[krow][c4 << 2] =
          *(const float4*)(W + (long long)(kt + krow) * ldw + (c4 << 2));
    }
    __syncthreads();
#pragma unroll
    for (int kk = 0; kk < BK; ++kk) {
      float a[TM], b[TN];
      if constexpr (TM % 4 == 0) {
#pragma unroll
        for (int i = 0; i < TM; i += 4)
          *(float4*)&a[i] = *(const float4*)&As[kk][ty * TM + i];
      } else {
#pragma unroll
        for (int i = 0; i < TM; ++i) a[i] = As[kk][ty * TM + i];
      }
      *(float4*)&b[0] = *(const float4*)&Ws[kk][tx * TN];
#pragma unroll
      for (int i = 0; i < TM; ++i)
#pragma unroll
        for (int j = 0; j < TN; ++j)
          acc[i][j] = fmaf(a[i], b[j], acc[i][j]);
    }
    __syncthreads();
  }

#pragma unroll
  for (int i = 0; i < TM; ++i) {
    int r = bm0 + ty * TM + i;
    if (r >= M) continue;
    float4 v = make_float4(acc[i][0], acc[i][1], acc[i][2], acc[i][3]);
    if (biasp != nullptr) {
      v.x += biasp[tx * TN + 0]; v.y += biasp[tx * TN + 1];
      v.z += biasp[tx * TN + 2]; v.w += biasp[tx * TN + 3];
    }
    *(float4*)(Cv + (long long)r * ldc + bn0 + tx * TN) = v;
  }
}

// ---------------------------------------------------------------------------
// Weight fusion stage 1: T1 = wgc1@wgc2, T2 = lin1@wgc2, ta = bgc1@wgc2,
// tb = lin1b@wgc2  (all K=128 dots)
// ---------------------------------------------------------------------------
__global__ __launch_bounds__(256)
void fuse1_k(const float* __restrict__ wgc1, const float* __restrict__ lin1,
             const float* __restrict__ bgc1, const float* __restrict__ lin1b,
             const float* __restrict__ wgc2,
             float* __restrict__ T1, float* __restrict__ T2,
             float* __restrict__ ta, float* __restrict__ tb)
{
  int t = blockIdx.x * 256 + threadIdx.x;
  const float* Arow; float* outp; int n;
  if (t < 32768)      { n = t & 127; Arow = wgc1 + (t >> 7) * 128; outp = T1 + t; }
  else if (t < 65536) { int u = t - 32768; n = u & 127; Arow = lin1 + (u >> 7) * 128; outp = T2 + u; }
  else if (t < 65664) { n = t - 65536; Arow = bgc1;  outp = ta + n; }
  else if (t < 65792) { n = t - 65664; Arow = lin1b; outp = tb + n; }
  else return;
  float s = 0.f;
  for (int k = 0; k < 128; ++k) s = fmaf(Arow[k], wgc2[k * 128 + n], s);
  *outp = s;
}

// ---------------------------------------------------------------------------
// Weight fusion stage 2: Wab[:,0:64] = T1@w2, Wab[:,64:128] = T2@w2,
// bab = [ta@w2 | tb@w2], bc = bgc2@w2
// ---------------------------------------------------------------------------
__global__ __launch_bounds__(256)
void fuse2_k(const float* __restrict__ T1, const float* __restrict__ T2,
             const float* __restrict__ ta, const float* __restrict__ tb,
             const float* __restrict__ bgc2, const float* __restrict__ w2,
             float* __restrict__ Wab, float* __restrict__ bab,
             float* __restrict__ bcv)
{
  int t = blockIdx.x * 256 + threadIdx.x;
  const float* Arow; float* outp; int j;
  if (t < 32768) {
    int c = t & 127; j = c & 63;
    Arow = (c < 64 ? T1 : T2) + (t >> 7) * 128;
    outp = Wab + t;
  } else if (t < 32896) {
    int c = t - 32768; j = c & 63; Arow = (c < 64) ? ta : tb; outp = bab + c;
  } else if (t < 32960) {
    j = t - 32896; Arow = bgc2; outp = bcv + j;
  } else return;
  float s = 0.f;
  for (int k = 0; k < 128; ++k) s = fmaf(Arow[k], w2[k * 64 + j], s);
  *outp = s;
}

// ---------------------------------------------------------------------------
// CSR build: histogram -> 3-pass exclusive scan -> scatter permutation
// ---------------------------------------------------------------------------
__global__ __launch_bounds__(256)
void hist_k(const int* __restrict__ dst, int* __restrict__ cur)
{
  int e = blockIdx.x * 256 + threadIdx.x;
  if (e < EE) atomicAdd(&cur[dst[e]], 1);
}

__global__ __launch_bounds__(256)
void scan1_k(const int* __restrict__ cnt, int* __restrict__ rp1,
             int* __restrict__ part, int n)
{
  __shared__ int s[256];
  int t = threadIdx.x;
  int base = blockIdx.x * 1024 + t * 4;
  int a0 = (base + 0 < n) ? cnt[base + 0] : 0;
  int a1 = (base + 1 < n) ? cnt[base + 1] : 0;
  int a2 = (base + 2 < n) ? cnt[base + 2] : 0;
  int a3 = (base + 3 < n) ? cnt[base + 3] : 0;
  s[t] = a0 + a1 + a2 + a3;
  __syncthreads();
  for (int off = 1; off < 256; off <<= 1) {
    int v = (t >= off) ? s[t - off] : 0;
    __syncthreads();
    s[t] += v;
    __syncthreads();
  }
  int pre = t ? s[t - 1] : 0;
  int r0 = pre + a0, r1 = r0 + a1, r2 = r1 + a2, r3 = r2 + a3;
  if (base + 0 < n) rp1[base + 0] = r0;
  if (base + 1 < n) rp1[base + 1] = r1;
  if (base + 2 < n) rp1[base + 2] = r2;
  if (base + 3 < n) rp1[base + 3] = r3;
  if (t == 255) part[blockIdx.x] = s[255];
}

__global__ __launch_bounds__(256)
void scan2_k(int* __restrict__ part, int nb)
{
  __shared__ int s[256];
  int t = threadIdx.x;
  int v = (t < nb) ? part[t] : 0;
  s[t] = v;
  __syncthreads();
  for (int off = 1; off < 256; off <<= 1) {
    int u = (t >= off) ? s[t - off] : 0;
    __syncthreads();
    s[t] += u;
    __syncthreads();
  }
  if (t < nb) part[t] = s[t] - v;     // exclusive
}

__global__ __launch_bounds__(256)
void scan3_k(int* __restrict__ rp, const int* __restrict__ part, int n)
{
  int i = blockIdx.x * 256 + threadIdx.x;
  if (i == 0) rp[0] = 0;
  if (i < n) rp[1 + i] += part[i >> 10];
}

__global__ __launch_bounds__(256)
void scatter_k(const int* __restrict__ dst, const int* __restrict__ rp,
               int* __restrict__ cur, int* __restrict__ perm)
{
  int e = blockIdx.x * 256 + threadIdx.x;
  if (e >= EE) return;
  int d = dst[e];
  int pos = rp[d] + atomicAdd(&cur[d], 1);
  perm[pos] = e;
}

// ---------------------------------------------------------------------------
// CSR spmm on 64-wide f32 rows (src row stride GLD): one wave per dst node,
// lane owns one column. Int fixed-point accumulate -> bit-deterministic.
//  MODE 1: out = acc*INVS + bias[lane]
//  MODE 2: out = n[d]*P[d,lane] + (1-n[d])*acc*INVS + bias[lane]
//          (P = QP[:,64:128], the fused combine epilogue)
// ---------------------------------------------------------------------------
template<int MODE, int GLD>
__global__ __launch_bounds__(256)
void spmm64(const int* __restrict__ rp, const int* __restrict__ perm,
            const int* __restrict__ esrc, const float* __restrict__ ew,
            const float* __restrict__ Gf, float* __restrict__ xout,
            const float* __restrict__ bias, const float* __restrict__ npar,
            const float* __restrict__ QP)
{
  int widx = blockIdx.x * 4 + (threadIdx.x >> 6);
  if (widx >= NN) return;
  int lane = threadIdx.x & 63;
  int e0 = rp[widx], e1 = rp[widx + 1];
  int acc = 0;
  for (int g0 = e0; g0 < e1; g0 += 64) {
    int ee = g0 + lane;
    int s = 0; float w = 0.f;
    if (ee < e1) {
      int p = perm[ee];
      s = esrc[p];
      w = ew[p];
    }
    int m = e1 - g0; if (m > 64) m = 64;
    int j = 0;
    for (; j + 8 <= m; j += 8) {
      float gv[8], wv[8];
#pragma unroll
      for (int u = 0; u < 8; ++u) {
        int sj = __shfl(s, j + u, 64);
        wv[u] = __shfl(w, j + u, 64);
        gv[u] = Gf[(size_t)sj * GLD + lane];
      }
#pragma unroll
      for (int u = 0; u < 8; ++u)
        acc += __float2int_rn(gv[u] * wv[u] * FIXS);
    }
    for (; j < m; ++j) {
      int sj = __shfl(s, j, 64);
      float wj = __shfl(w, j, 64);
      acc += __float2int_rn(Gf[(size_t)sj * GLD + lane] * wj * FIXS);
    }
  }
  float v = (float)acc * INVS;
  if (MODE == 1) {
    xout[(size_t)widx * 64 + lane] = v + bias[lane];
  } else {
    float nv = npar[widx];
    float p = QP[(size_t)widx * 128 + 64 + lane];
    xout[(size_t)widx * 64 + lane] = nv * p + (1.f - nv) * v + bias[lane];
  }
}

// ---------------------------------------------------------------------------
// S[b,:] = sum_l Z[bidx[b,l],:] - 49*b2   (Z rows already carry +b2 each)
// ---------------------------------------------------------------------------
__global__ __launch_bounds__(256)
void sumS_k(const float* __restrict__ Z, const int* __restrict__ bidx,
            const float* __restrict__ b2, float* __restrict__ S)
{
  int wv = threadIdx.x >> 6;
  int lane = threadIdx.x & 63;
  int b = blockIdx.x * 4 + wv;
  if (b >= BBB) return;
  const int* bi = bidx + (size_t)b * LLL;
  float s = 0.f;
  for (int l = 0; l < LLL; ++l)
    s += Z[(size_t)bi[l] * 64 + lane];
  S[(size_t)b * 64 + lane] = s - 49.f * b2[lane];
}

// ---------------------------------------------------------------------------
// sel = P4[0]+P4[1]+P4[2]+P4[3] + l1b  (fixed order -> deterministic)
// ---------------------------------------------------------------------------
__global__ __launch_bounds__(256)
void reduce4_k(const float* __restrict__ P4, const float* __restrict__ l1b,
               float* __restrict__ sel)
{
  int t = blockIdx.x * 256 + threadIdx.x;
  if (t >= BBB * 32) return;
  int r = t >> 5, c4 = t & 31;
  size_t off = (size_t)r * 128 + (c4 << 2);
  const size_t zs = (size_t)BBB * 128;
  float4 s0 = *(const float4*)(P4 + off);
  float4 s1 = *(const float4*)(P4 + zs + off);
  float4 s2 = *(const float4*)(P4 + 2 * zs + off);
  float4 s3 = *(const float4*)(P4 + 3 * zs + off);
  float4 b  = *(const float4*)(l1b + (c4 << 2));
  float4 o;
  o.x = ((s0.x + s1.x) + s2.x) + s3.x + b.x;
  o.y = ((s0.y + s1.y) + s2.y) + s3.y + b.y;
  o.z = ((s0.z + s1.z) + s2.z) + s3.z + b.z;
  o.w = ((s0.w + s1.w) + s2.w) + s3.w + b.w;
  *(float4*)(sel + off) = o;
}

// ---------------------------------------------------------------------------
// Classifier + argmax (first-max tie-break, matches jnp.argmax).
// ---------------------------------------------------------------------------
__global__ __launch_bounds__(256)
void cls_k(const float* __restrict__ sel, const float* __restrict__ Wc,
           const float* __restrict__ bc, float* __restrict__ outIdx)
{
  int wv = threadIdx.x >> 6;
  int lane = threadIdx.x & 63;
  int b = blockIdx.x * 4 + wv;
  if (b >= BBB) return;
  float logit = -1e30f;
  if (lane < NCLS) {
    float s = bc[lane];
    const float* sr = sel + (size_t)b * DD;
    for (int d = 0; d < DD; ++d) s = fmaf(sr[d], Wc[d * NCLS + lane], s);
    logit = s;
  }
  float best = -1e30f; int bi = 0;
  for (int c = 0; c < NCLS; ++c) {
    float v = __shfl(logit, c, 64);
    if (v > best) { best = v; bi = c; }
  }
  if (lane == 0) outIdx[b] = (float)bi;
}

// ---------------------------------------------------------------------------
extern "C" void kernel_launch(void* const* d_in, const int* in_sizes, int n_in,
                              void* d_out, int out_size, void* d_ws, size_t ws_size,
                              hipStream_t stream)
{
  const float* A1    = (const float*)d_in[0];
  const int*   esrc  = (const int*)d_in[1];
  const int*   edst  = (const int*)d_in[2];
  const float* ew    = (const float*)d_in[3];
  const int*   bidx  = (const int*)d_in[4];   // [B,1,L] == [B*L]
  const float* wgc1  = (const float*)d_in[5];
  const float* bgc1  = (const float*)d_in[6];
  const float* wgc2  = (const float*)d_in[7];
  const float* bgc2  = (const float*)d_in[8];
  const float* npar  = (const float*)d_in[9];
  const float* lin1  = (const float*)d_in[10];
  const float* lin1b = (const float*)d_in[11];
  const float* w2    = (const float*)d_in[12];
  const float* b2    = (const float*)d_in[13];
  const float* l1w   = (const float*)d_in[14];
  const float* l1b   = (const float*)d_in[15];
  const float* clsw  = (const float*)d_in[16];
  const float* clsb  = (const float*)d_in[17];

  float* out = (float*)d_out;
  float* sel = out + BBB;

  // workspace layout (peak ~85.5 MB; proven floor from round 1 is 104.67 MB)
  uint8_t* ws   = (uint8_t*)d_ws;
  float*   QP   = (float*)(ws);                 // 51.2 MB [N,128]; Z reuses 1st half
  float*   G    = (float*)(ws + 51200000);      // 25.6 MB [N,64]; P4 reuses it
  float*   Z    = (float*)(ws);                 // 25.6 MB [N,64] (over QP)
  float*   P4   = (float*)(ws + 51200000);      //  8.4 MB 4x[B,128] (over G)
  int*     perm = (int*)  (ws + 76800000);      //  6.4 MB
  int*     rp   = (int*)  (ws + 83200000);      //  0.4 MB (N+1)
  int*     cur  = (int*)  (ws + 83600016);      //  0.4 MB
  int*     part = (int*)  (ws + 84000016);      //  512 B
  float*   S    = (float*)(ws + 84000528);      //  1.0 MB [B,64]
  float*   T1   = (float*)(ws + 85049104);      // 128 KB [256,128]
  float*   T2   = (float*)(ws + 85180176);      // 128 KB
  float*   Wab  = (float*)(ws + 85311248);      // 128 KB [256,128]
  float*   ta   = (float*)(ws + 85442320);      // 512 B
  float*   tb   = (float*)(ws + 85442832);      // 512 B
  float*   bab  = (float*)(ws + 85443344);      // 512 B [128]
  float*   bcv  = (float*)(ws + 85443856);      // 256 B [64]

  dim3 blk(256);

  // ---- weight fusion (2 launches) ----
  hipLaunchKernelGGL(fuse1_k, dim3(257), blk, 0, stream,
      wgc1, lin1, bgc1, lin1b, wgc2, T1, T2, ta, tb);
  hipLaunchKernelGGL(fuse2_k, dim3(129), blk, 0, stream,
      T1, T2, ta, tb, bgc2, w2, Wab, bab, bcv);

  // ---- CSR build (shared by both spmms) ----
  hipMemsetAsync(cur, 0, NN * 4, stream);
  hipLaunchKernelGGL(hist_k, dim3(EE / 256), blk, 0, stream, edst, cur);
  hipLaunchKernelGGL(scan1_k, dim3(98), blk, 0, stream, cur, rp + 1, part, NN);
  hipLaunchKernelGGL(scan2_k, dim3(1), blk, 0, stream, part, 98);
  hipLaunchKernelGGL(scan3_k, dim3(391), blk, 0, stream, rp, part, NN);
  hipMemsetAsync(cur, 0, NN * 4, stream);
  hipLaunchKernelGGL(scatter_k, dim3(EE / 256), blk, 0, stream, edst, rp, cur, perm);

  // ---- QP = A1 @ Wab + bab  [N,128]  (Q = cols 0..63, P = cols 64..127) ----
  hipLaunchKernelGGL((gemm_f32<64,128,16,8,4>), dim3(1563, 1, 1), blk, 0, stream,
      A1, EMBD, Wab, 128, bab, QP, 128,
      NN, EMBD, EMBD, (const int*)nullptr, (const float*)nullptr);

  // ---- G = n*P + (1-n)*spmm(Q) + bc   (combine fused into spmm epilogue) ----
  hipLaunchKernelGGL((spmm64<2,128>), dim3(NN / 4), blk, 0, stream,
      rp, perm, esrc, ew, QP, G, bcv, npar, QP);

  // ---- Z = spmm(G) + b2  [N,64] (overwrites QP's first half) ----
  hipLaunchKernelGGL((spmm64<1,64>), dim3(NN / 4), blk, 0, stream,
      rp, perm, esrc, ew, G, Z, b2, (const float*)nullptr, (const float*)nullptr);

  // ---- S[b] = sum_l Z[bidx[b,l]] - 49*b2 ----
  hipLaunchKernelGGL(sumS_k, dim3(BBB / 4), blk, 0, stream, Z, bidx, b2, S);

  // ---- P4[z] = [gather(Z)|S] @ l1w (K-chunk z)  grid (128,2,4) ----
  hipLaunchKernelGGL((gemm_f32<32,64,32,2,4>), dim3(BBB / 32, 2, 4), blk, 0, stream,
      Z, 64, l1w, DD, (const float*)nullptr, P4, DD,
      BBB, (LLL + 1) * 64, 13 * 64, bidx, S);

  // ---- sel = sum_z P4[z] + l1b ----
  hipLaunchKernelGGL(reduce4_k, dim3(BBB * 32 / 256), blk, 0, stream, P4, l1b, sel);

  // ---- argmax(sel @ classifier + bias) -> out[0:B] ----
  hipLaunchKernelGGL(cls_k, dim3(BBB / 4), blk, 0, stream, sel, clsw, clsb, out);
}

// Round 7
// 529.588 us; speedup vs baseline: 9.2145x; 1.1352x over previous
//
#include <hip/hip_runtime.h>
#include <cstdint>

#define NN   100000
#define EE   1600000
#define EMBD 256
#define DD   128
#define BBB  4096
#define LLL  50
#define NCLS 10

#define NB   196                  /* coarse buckets of 512 dst nodes */
#define BSH  9
#define EPB  4096                 /* edges per bin_k block */

#define FIXS 1048576.0f           /* 2^20 fixed-point scale for spmm accum */
#define INVS (1.0f / 1048576.0f)

// ---------------------------------------------------------------------------
// fp32 tiled GEMM: C[M, BN(grid.y)] = A[M,K] @ W[K,*] (+bias)
//  grid.z splits K into chunks of kper; chunk z writes C + z*M*ldc.
//  bidxg!=null: gather-A mode: A(r,k) =
//      k<3200 ? Z[bidx[r*50 + k/64]*64 + k%64] : S[r*64 + k%64]
// ---------------------------------------------------------------------------
template<int BM, int BN, int BK, int TM, int TN>
__global__ __launch_bounds__(256)
void gemm_f32(const float* __restrict__ Av, int lda,
              const float* __restrict__ W, int ldw,
              const float* __restrict__ bias,
              float* __restrict__ Cv, int ldc,
              int M, int ktot, int kper,
              const int* __restrict__ bidxg,
              const float* __restrict__ Sg)
{
  constexpr int TX = BN / TN;
  constexpr int TY = BM / TM;
  static_assert(TX * TY == 256, "thread mapping");
  static_assert(TN == 4, "epilogue uses 4-wide vectors");
  constexpr int AQ = BK / 4;
  static_assert(BM * AQ == 256, "A-tile load mapping");

  __shared__ float As[BK][BM + 4];
  __shared__ float Ws[BK][BN];

  const int tid = threadIdx.x;
  const int tx = tid % TX, ty = tid / TX;
  const int bm0 = blockIdx.x * BM;
  const int bn0 = blockIdx.y * BN;
  const int z = blockIdx.z;
  const int koff = z * kper;
  int kc = ktot - koff; if (kc > kper) kc = kper;
  W += bn0 + (size_t)koff * ldw;
  Cv += (size_t)z * (size_t)M * ldc;
  const float* biasp = bias ? bias + bn0 : nullptr;

  float acc[TM][TN];
#pragma unroll
  for (int i = 0; i < TM; ++i)
#pragma unroll
    for (int j = 0; j < TN; ++j) acc[i][j] = 0.f;

  const int arow_l = tid / AQ;
  const int akq = tid % AQ;
  const int arow_g = bm0 + arow_l;
  const bool arow_ok = arow_g < M;
  const long long asrc = (long long)arow_g * lda + koff;

  constexpr int WQ4 = BN / 4;
  constexpr int WLOADS = (BK * WQ4) / 256;

  for (int kt = 0; kt < kc; kt += BK) {
    float4 av = make_float4(0.f, 0.f, 0.f, 0.f);
    if (arow_ok) {
      if (bidxg) {
        int k = koff + kt + (akq << 2);
        int l = k >> 6, j = k & 63;
        const float* ap = (l < LLL)
            ? (Av + (size_t)bidxg[arow_g * LLL + l] * 64 + j)
            : (Sg + (size_t)arow_g * 64 + j);
        av = *(const float4*)ap;
      } else {
        av = *(const float4*)(Av + asrc + kt + (akq << 2));
      }
    }
    As[(akq << 2) + 0][arow_l] = av.x;
    As[(akq << 2) + 1][arow_l] = av.y;
    As[(akq << 2) + 2][arow_l] = av.z;
    As[(akq << 2) + 3][arow_l] = av.w;
#pragma unroll
    for (int p = 0; p < WLOADS; ++p) {
      int f = tid + p * 256;
      int krow = f / WQ4, c4 = f % WQ4;
      *(float4*)&Ws[krow][c4 << 2] =
          *(const float4*)(W + (long long)(kt + krow) * ldw + (c4 << 2));
    }
    __syncthreads();
#pragma unroll
    for (int kk = 0; kk < BK; ++kk) {
      float a[TM], b[TN];
      if constexpr (TM % 4 == 0) {
#pragma unroll
        for (int i = 0; i < TM; i += 4)
          *(float4*)&a[i] = *(const float4*)&As[kk][ty * TM + i];
      } else {
#pragma unroll
        for (int i = 0; i < TM; ++i) a[i] = As[kk][ty * TM + i];
      }
      *(float4*)&b[0] = *(const float4*)&Ws[kk][tx * TN];
#pragma unroll
      for (int i = 0; i < TM; ++i)
#pragma unroll
        for (int j = 0; j < TN; ++j)
          acc[i][j] = fmaf(a[i], b[j], acc[i][j]);
    }
    __syncthreads();
  }

#pragma unroll
  for (int i = 0; i < TM; ++i) {
    int r = bm0 + ty * TM + i;
    if (r >= M) continue;
    float4 v = make_float4(acc[i][0], acc[i][1], acc[i][2], acc[i][3]);
    if (biasp != nullptr) {
      v.x += biasp[tx * TN + 0]; v.y += biasp[tx * TN + 1];
      v.z += biasp[tx * TN + 2]; v.w += biasp[tx * TN + 3];
    }
    *(float4*)(Cv + (long long)r * ldc + bn0 + tx * TN) = v;
  }
}

// ---------------------------------------------------------------------------
// Weight fusion stage 1: T1 = wgc1@wgc2, T2 = lin1@wgc2, ta = bgc1@wgc2,
// tb = lin1b@wgc2  (all K=128 dots)
// ---------------------------------------------------------------------------
__global__ __launch_bounds__(256)
void fuse1_k(const float* __restrict__ wgc1, const float* __restrict__ lin1,
             const float* __restrict__ bgc1, const float* __restrict__ lin1b,
             const float* __restrict__ wgc2,
             float* __restrict__ T1, float* __restrict__ T2,
             float* __restrict__ ta, float* __restrict__ tb)
{
  int t = blockIdx.x * 256 + threadIdx.x;
  const float* Arow; float* outp; int n;
  if (t < 32768)      { n = t & 127; Arow = wgc1 + (t >> 7) * 128; outp = T1 + t; }
  else if (t < 65536) { int u = t - 32768; n = u & 127; Arow = lin1 + (u >> 7) * 128; outp = T2 + u; }
  else if (t < 65664) { n = t - 65536; Arow = bgc1;  outp = ta + n; }
  else if (t < 65792) { n = t - 65664; Arow = lin1b; outp = tb + n; }
  else return;
  float s = 0.f;
  for (int k = 0; k < 128; ++k) s = fmaf(Arow[k], wgc2[k * 128 + n], s);
  *outp = s;
}

// ---------------------------------------------------------------------------
// Weight fusion stage 2: Wab[:,0:64] = T1@w2, Wab[:,64:128] = T2@w2,
// bab = [ta@w2 | tb@w2], bc = bgc2@w2
// ---------------------------------------------------------------------------
__global__ __launch_bounds__(256)
void fuse2_k(const float* __restrict__ T1, const float* __restrict__ T2,
             const float* __restrict__ ta, const float* __restrict__ tb,
             const float* __restrict__ bgc2, const float* __restrict__ w2,
             float* __restrict__ Wab, float* __restrict__ bab,
             float* __restrict__ bcv)
{
  int t = blockIdx.x * 256 + threadIdx.x;
  const float* Arow; float* outp; int j;
  if (t < 32768) {
    int c = t & 127; j = c & 63;
    Arow = (c < 64 ? T1 : T2) + (t >> 7) * 128;
    outp = Wab + t;
  } else if (t < 32896) {
    int c = t - 32768; j = c & 63; Arow = (c < 64) ? ta : tb; outp = bab + c;
  } else if (t < 32960) {
    j = t - 32896; Arow = bgc2; outp = bcv + j;
  } else return;
  float s = 0.f;
  for (int k = 0; k < 128; ++k) s = fmaf(Arow[k], w2[k * 64 + j], s);
  *outp = s;
}

// ---------------------------------------------------------------------------
// CSR build: fine histogram -> 3-pass exclusive scan (-> rp), then
// two-level locality-friendly placement (bin_k -> sort_k) replacing the
// write-amplified single-pass scatter.
// ---------------------------------------------------------------------------
__global__ __launch_bounds__(256)
void hist_k(const int* __restrict__ dst, int* __restrict__ cur)
{
  int e = blockIdx.x * 256 + threadIdx.x;
  if (e < EE) atomicAdd(&cur[dst[e]], 1);
}

__global__ __launch_bounds__(256)
void scan1_k(const int* __restrict__ cnt, int* __restrict__ rp1,
             int* __restrict__ part, int n)
{
  __shared__ int s[256];
  int t = threadIdx.x;
  int base = blockIdx.x * 1024 + t * 4;
  int a0 = (base + 0 < n) ? cnt[base + 0] : 0;
  int a1 = (base + 1 < n) ? cnt[base + 1] : 0;
  int a2 = (base + 2 < n) ? cnt[base + 2] : 0;
  int a3 = (base + 3 < n) ? cnt[base + 3] : 0;
  s[t] = a0 + a1 + a2 + a3;
  __syncthreads();
  for (int off = 1; off < 256; off <<= 1) {
    int v = (t >= off) ? s[t - off] : 0;
    __syncthreads();
    s[t] += v;
    __syncthreads();
  }
  int pre = t ? s[t - 1] : 0;
  int r0 = pre + a0, r1 = r0 + a1, r2 = r1 + a2, r3 = r2 + a3;
  if (base + 0 < n) rp1[base + 0] = r0;
  if (base + 1 < n) rp1[base + 1] = r1;
  if (base + 2 < n) rp1[base + 2] = r2;
  if (base + 3 < n) rp1[base + 3] = r3;
  if (t == 255) part[blockIdx.x] = s[255];
}

__global__ __launch_bounds__(256)
void scan2_k(int* __restrict__ part, int nb)
{
  __shared__ int s[256];
  int t = threadIdx.x;
  int v = (t < nb) ? part[t] : 0;
  s[t] = v;
  __syncthreads();
  for (int off = 1; off < 256; off <<= 1) {
    int u = (t >= off) ? s[t - off] : 0;
    __syncthreads();
    s[t] += u;
    __syncthreads();
  }
  if (t < nb) part[t] = s[t] - v;     // exclusive
}

__global__ __launch_bounds__(256)
void scan3_k(int* __restrict__ rp, const int* __restrict__ part, int n)
{
  int i = blockIdx.x * 256 + threadIdx.x;
  if (i == 0) rp[0] = 0;
  if (i < n) rp[1 + i] += part[i >> 10];
}

// gcur[c] = rp[c*512]  (coarse bucket write cursors)
__global__ __launch_bounds__(256)
void initcur_k(const int* __restrict__ rp, int* __restrict__ gcur)
{
  int t = threadIdx.x;
  if (t < NB) gcur[t] = rp[t << BSH];
}

// Level 1: bin edges into coarse buckets; per-block contiguous runs.
__global__ __launch_bounds__(256)
void bin_k(const int* __restrict__ edst, int* __restrict__ gcur,
           int2* __restrict__ ebd)
{
  __shared__ int lcnt[NB];
  __shared__ int lbase[NB];
  const int tid = threadIdx.x;
  const int e0 = blockIdx.x * EPB;
  const int e1 = min(EE, e0 + EPB);
  for (int i = tid; i < NB; i += 256) lcnt[i] = 0;
  __syncthreads();
  int dv[16];
#pragma unroll
  for (int u = 0; u < 16; ++u) {
    int e = e0 + u * 256 + tid;
    dv[u] = (e < e1) ? edst[e] : -1;
    if (dv[u] >= 0) atomicAdd(&lcnt[dv[u] >> BSH], 1);
  }
  __syncthreads();
  for (int i = tid; i < NB; i += 256) {
    lbase[i] = atomicAdd(&gcur[i], lcnt[i]);
    lcnt[i] = 0;
  }
  __syncthreads();
#pragma unroll
  for (int u = 0; u < 16; ++u) {
    int e = e0 + u * 256 + tid;
    if (dv[u] >= 0) {
      int c = dv[u] >> BSH;
      int k = atomicAdd(&lcnt[c], 1);
      int2 p; p.x = e; p.y = dv[u];
      ebd[lbase[c] + k] = p;
    }
  }
}

// Level 2: one block per bucket; place into perm via LDS row counters.
// perm writes stay inside a ~32KB L2-resident window -> no amplification.
__global__ __launch_bounds__(256)
void sort_k(const int2* __restrict__ ebd, const int* __restrict__ rp,
            int* __restrict__ perm)
{
  __shared__ int rpl[512];
  __shared__ int lcur[512];
  const int c = blockIdx.x;
  const int n0 = c << BSH;
  const int n1 = min(NN, n0 + 512);
  const int nn = n1 - n0;
  const int tid = threadIdx.x;
  for (int i = tid; i < nn; i += 256) { rpl[i] = rp[n0 + i]; lcur[i] = 0; }
  __syncthreads();
  const int b0 = rp[n0];
  const int b1 = rp[n1];
  for (int i = b0 + tid; i < b1; i += 256) {
    int2 p = ebd[i];
    int li = p.y - n0;
    int k = atomicAdd(&lcur[li], 1);
    perm[rpl[li] + k] = p.x;
  }
}

// ---------------------------------------------------------------------------
// CSR spmm on 64-wide f32 rows (src row stride GLD): one wave per dst node,
// lane owns one column. Int fixed-point accumulate -> bit-deterministic.
//  MODE 1: out = acc*INVS + bias[lane]
//  MODE 2: out = n[d]*P[d,lane] + (1-n[d])*acc*INVS + bias[lane]
// ---------------------------------------------------------------------------
template<int MODE, int GLD>
__global__ __launch_bounds__(256)
void spmm64(const int* __restrict__ rp, const int* __restrict__ perm,
            const int* __restrict__ esrc, const float* __restrict__ ew,
            const float* __restrict__ Gf, float* __restrict__ xout,
            const float* __restrict__ bias, const float* __restrict__ npar,
            const float* __restrict__ QP)
{
  int widx = blockIdx.x * 4 + (threadIdx.x >> 6);
  if (widx >= NN) return;
  int lane = threadIdx.x & 63;
  int e0 = rp[widx], e1 = rp[widx + 1];
  int acc = 0;
  for (int g0 = e0; g0 < e1; g0 += 64) {
    int ee = g0 + lane;
    int s = 0; float w = 0.f;
    if (ee < e1) {
      int p = perm[ee];
      s = esrc[p];
      w = ew[p];
    }
    int m = e1 - g0; if (m > 64) m = 64;
    int j = 0;
    for (; j + 8 <= m; j += 8) {
      float gv[8], wv[8];
#pragma unroll
      for (int u = 0; u < 8; ++u) {
        int sj = __shfl(s, j + u, 64);
        wv[u] = __shfl(w, j + u, 64);
        gv[u] = Gf[(size_t)sj * GLD + lane];
      }
#pragma unroll
      for (int u = 0; u < 8; ++u)
        acc += __float2int_rn(gv[u] * wv[u] * FIXS);
    }
    for (; j < m; ++j) {
      int sj = __shfl(s, j, 64);
      float wj = __shfl(w, j, 64);
      acc += __float2int_rn(Gf[(size_t)sj * GLD + lane] * wj * FIXS);
    }
  }
  float v = (float)acc * INVS;
  if (MODE == 1) {
    xout[(size_t)widx * 64 + lane] = v + bias[lane];
  } else {
    float nv = npar[widx];
    float p = QP[(size_t)widx * 128 + 64 + lane];
    xout[(size_t)widx * 64 + lane] = nv * p + (1.f - nv) * v + bias[lane];
  }
}

// ---------------------------------------------------------------------------
// S[b,:] = sum_l Z[bidx[b,l],:] - 49*b2   (Z rows already carry +b2 each)
// ---------------------------------------------------------------------------
__global__ __launch_bounds__(256)
void sumS_k(const float* __restrict__ Z, const int* __restrict__ bidx,
            const float* __restrict__ b2, float* __restrict__ S)
{
  int wv = threadIdx.x >> 6;
  int lane = threadIdx.x & 63;
  int b = blockIdx.x * 4 + wv;
  if (b >= BBB) return;
  const int* bi = bidx + (size_t)b * LLL;
  float s = 0.f;
  for (int l = 0; l < LLL; ++l)
    s += Z[(size_t)bi[l] * 64 + lane];
  S[(size_t)b * 64 + lane] = s - 49.f * b2[lane];
}

// ---------------------------------------------------------------------------
// sel = P4[0]+P4[1]+P4[2]+P4[3] + l1b  (fixed order -> deterministic)
// ---------------------------------------------------------------------------
__global__ __launch_bounds__(256)
void reduce4_k(const float* __restrict__ P4, const float* __restrict__ l1b,
               float* __restrict__ sel)
{
  int t = blockIdx.x * 256 + threadIdx.x;
  if (t >= BBB * 32) return;
  int r = t >> 5, c4 = t & 31;
  size_t off = (size_t)r * 128 + (c4 << 2);
  const size_t zs = (size_t)BBB * 128;
  float4 s0 = *(const float4*)(P4 + off);
  float4 s1 = *(const float4*)(P4 + zs + off);
  float4 s2 = *(const float4*)(P4 + 2 * zs + off);
  float4 s3 = *(const float4*)(P4 + 3 * zs + off);
  float4 b  = *(const float4*)(l1b + (c4 << 2));
  float4 o;
  o.x = ((s0.x + s1.x) + s2.x) + s3.x + b.x;
  o.y = ((s0.y + s1.y) + s2.y) + s3.y + b.y;
  o.z = ((s0.z + s1.z) + s2.z) + s3.z + b.z;
  o.w = ((s0.w + s1.w) + s2.w) + s3.w + b.w;
  *(float4*)(sel + off) = o;
}

// ---------------------------------------------------------------------------
// Classifier + argmax (first-max tie-break, matches jnp.argmax).
// ---------------------------------------------------------------------------
__global__ __launch_bounds__(256)
void cls_k(const float* __restrict__ sel, const float* __restrict__ Wc,
           const float* __restrict__ bc, float* __restrict__ outIdx)
{
  int wv = threadIdx.x >> 6;
  int lane = threadIdx.x & 63;
  int b = blockIdx.x * 4 + wv;
  if (b >= BBB) return;
  float logit = -1e30f;
  if (lane < NCLS) {
    float s = bc[lane];
    const float* sr = sel + (size_t)b * DD;
    for (int d = 0; d < DD; ++d) s = fmaf(sr[d], Wc[d * NCLS + lane], s);
    logit = s;
  }
  float best = -1e30f; int bi = 0;
  for (int c = 0; c < NCLS; ++c) {
    float v = __shfl(logit, c, 64);
    if (v > best) { best = v; bi = c; }
  }
  if (lane == 0) outIdx[b] = (float)bi;
}

// ---------------------------------------------------------------------------
extern "C" void kernel_launch(void* const* d_in, const int* in_sizes, int n_in,
                              void* d_out, int out_size, void* d_ws, size_t ws_size,
                              hipStream_t stream)
{
  const float* A1    = (const float*)d_in[0];
  const int*   esrc  = (const int*)d_in[1];
  const int*   edst  = (const int*)d_in[2];
  const float* ew    = (const float*)d_in[3];
  const int*   bidx  = (const int*)d_in[4];   // [B,1,L] == [B*L]
  const float* wgc1  = (const float*)d_in[5];
  const float* bgc1  = (const float*)d_in[6];
  const float* wgc2  = (const float*)d_in[7];
  const float* bgc2  = (const float*)d_in[8];
  const float* npar  = (const float*)d_in[9];
  const float* lin1  = (const float*)d_in[10];
  const float* lin1b = (const float*)d_in[11];
  const float* w2    = (const float*)d_in[12];
  const float* b2    = (const float*)d_in[13];
  const float* l1w   = (const float*)d_in[14];
  const float* l1b   = (const float*)d_in[15];
  const float* clsw  = (const float*)d_in[16];
  const float* clsb  = (const float*)d_in[17];

  float* out = (float*)d_out;
  float* sel = out + BBB;

  // workspace layout (peak ~98.3 MB; proven floor from round 1 is 104.67 MB)
  uint8_t* ws   = (uint8_t*)d_ws;
  float*   QP   = (float*)(ws);                 // 51.2 MB [N,128]; Z reuses 1st half
  float*   G    = (float*)(ws + 51200000);      // 25.6 MB [N,64]; P4 reuses it
  float*   Z    = (float*)(ws);                 // 25.6 MB [N,64] (over QP)
  float*   P4   = (float*)(ws + 51200000);      //  8.4 MB 4x[B,128] (over G)
  int*     perm = (int*)  (ws + 76800000);      //  6.4 MB
  int*     rp   = (int*)  (ws + 83200000);      //  0.4 MB (N+1)
  int*     cur  = (int*)  (ws + 83600016);      //  0.4 MB (hist; reused as gcur)
  int*     part = (int*)  (ws + 84000016);      //  512 B
  float*   S    = (float*)(ws + 84000528);      //  1.0 MB [B,64]
  float*   T1   = (float*)(ws + 85049104);      // 128 KB [256,128]
  float*   T2   = (float*)(ws + 85180176);      // 128 KB
  float*   Wab  = (float*)(ws + 85311248);      // 128 KB [256,128]
  float*   ta   = (float*)(ws + 85442320);      // 512 B
  float*   tb   = (float*)(ws + 85442832);      // 512 B
  float*   bab  = (float*)(ws + 85443344);      // 512 B [128]
  float*   bcv  = (float*)(ws + 85443856);      // 256 B [64]
  int2*    ebd  = (int2*) (ws + 85500000);      // 12.8 MB [E] (e,d) pairs

  dim3 blk(256);

  // ---- weight fusion (2 launches) ----
  hipLaunchKernelGGL(fuse1_k, dim3(257), blk, 0, stream,
      wgc1, lin1, bgc1, lin1b, wgc2, T1, T2, ta, tb);
  hipLaunchKernelGGL(fuse2_k, dim3(129), blk, 0, stream,
      T1, T2, ta, tb, bgc2, w2, Wab, bab, bcv);

  // ---- CSR build ----
  hipMemsetAsync(cur, 0, NN * 4, stream);
  hipLaunchKernelGGL(hist_k, dim3(EE / 256), blk, 0, stream, edst, cur);
  hipLaunchKernelGGL(scan1_k, dim3(98), blk, 0, stream, cur, rp + 1, part, NN);
  hipLaunchKernelGGL(scan2_k, dim3(1), blk, 0, stream, part, 98);
  hipLaunchKernelGGL(scan3_k, dim3(391), blk, 0, stream, rp, part, NN);
  hipLaunchKernelGGL(initcur_k, dim3(1), blk, 0, stream, rp, cur);
  hipLaunchKernelGGL(bin_k, dim3((EE + EPB - 1) / EPB), blk, 0, stream,
      edst, cur, ebd);
  hipLaunchKernelGGL(sort_k, dim3(NB), blk, 0, stream, ebd, rp, perm);

  // ---- QP = A1 @ Wab + bab  [N,128]  (Q = cols 0..63, P = cols 64..127) ----
  hipLaunchKernelGGL((gemm_f32<64,128,16,8,4>), dim3(1563, 1, 1), blk, 0, stream,
      A1, EMBD, Wab, 128, bab, QP, 128,
      NN, EMBD, EMBD, (const int*)nullptr, (const float*)nullptr);

  // ---- G = n*P + (1-n)*spmm(Q) + bc   (combine fused into spmm epilogue) ----
  hipLaunchKernelGGL((spmm64<2,128>), dim3(NN / 4), blk, 0, stream,
      rp, perm, esrc, ew, QP, G, bcv, npar, QP);

  // ---- Z = spmm(G) + b2  [N,64] (overwrites QP's first half) ----
  hipLaunchKernelGGL((spmm64<1,64>), dim3(NN / 4), blk, 0, stream,
      rp, perm, esrc, ew, G, Z, b2, (const float*)nullptr, (const float*)nullptr);

  // ---- S[b] = sum_l Z[bidx[b,l]] - 49*b2 ----
  hipLaunchKernelGGL(sumS_k, dim3(BBB / 4), blk, 0, stream, Z, bidx, b2, S);

  // ---- P4[z] = [gather(Z)|S] @ l1w (K-chunk z)  grid (128,2,4) ----
  hipLaunchKernelGGL((gemm_f32<32,64,32,2,4>), dim3(BBB / 32, 2, 4), blk, 0, stream,
      Z, 64, l1w, DD, (const float*)nullptr, P4, DD,
      BBB, (LLL + 1) * 64, 13 * 64, bidx, S);

  // ---- sel = sum_z P4[z] + l1b ----
  hipLaunchKernelGGL(reduce4_k, dim3(BBB * 32 / 256), blk, 0, stream, P4, l1b, sel);

  // ---- argmax(sel @ classifier + bias) -> out[0:B] ----
  hipLaunchKernelGGL(cls_k, dim3(BBB / 4), blk, 0, stream, sel, clsw, clsb, out);
}

// Round 8
// 471.763 us; speedup vs baseline: 10.3439x; 1.1226x over previous
//
#include <hip/hip_runtime.h>
#include <cstdint>

#define NN   100000
#define EE   1600000
#define EMBD 256
#define DD   128
#define BBB  4096
#define LLL  50
#define NCLS 10

#define NB   196                  /* coarse buckets of 512 dst nodes */
#define BSH  9
#define EPB  4096                 /* edges per bin_k block */

#define FIXS 1048576.0f           /* 2^20 fixed-point scale for spmm accum */
#define INVS (1.0f / 1048576.0f)

// ---------------------------------------------------------------------------
// fp32 tiled GEMM: C[M, BN(grid.y)] = A[M,K] @ W[K,*] (+bias)
//  grid.z splits K into chunks of kper; chunk z writes C + z*M*ldc.
//  bidxg!=null: gather-A mode: A(r,k) =
//      k<3200 ? Z[bidx[r*50 + k/64]*64 + k%64] : S[r*64 + k%64]
// ---------------------------------------------------------------------------
template<int BM, int BN, int BK, int TM, int TN>
__global__ __launch_bounds__(256)
void gemm_f32(const float* __restrict__ Av, int lda,
              const float* __restrict__ W, int ldw,
              const float* __restrict__ bias,
              float* __restrict__ Cv, int ldc,
              int M, int ktot, int kper,
              const int* __restrict__ bidxg,
              const float* __restrict__ Sg)
{
  constexpr int TX = BN / TN;
  constexpr int TY = BM / TM;
  static_assert(TX * TY == 256, "thread mapping");
  static_assert(TN == 4, "epilogue uses 4-wide vectors");
  constexpr int AQ = BK / 4;
  static_assert(BM * AQ == 256, "A-tile load mapping");

  __shared__ float As[BK][BM + 4];
  __shared__ float Ws[BK][BN];

  const int tid = threadIdx.x;
  const int tx = tid % TX, ty = tid / TX;
  const int bm0 = blockIdx.x * BM;
  const int bn0 = blockIdx.y * BN;
  const int z = blockIdx.z;
  const int koff = z * kper;
  int kc = ktot - koff; if (kc > kper) kc = kper;
  W += bn0 + (size_t)koff * ldw;
  Cv += (size_t)z * (size_t)M * ldc;
  const float* biasp = bias ? bias + bn0 : nullptr;

  float acc[TM][TN];
#pragma unroll
  for (int i = 0; i < TM; ++i)
#pragma unroll
    for (int j = 0; j < TN; ++j) acc[i][j] = 0.f;

  const int arow_l = tid / AQ;
  const int akq = tid % AQ;
  const int arow_g = bm0 + arow_l;
  const bool arow_ok = arow_g < M;
  const long long asrc = (long long)arow_g * lda + koff;

  constexpr int WQ4 = BN / 4;
  constexpr int WLOADS = (BK * WQ4) / 256;

  for (int kt = 0; kt < kc; kt += BK) {
    float4 av = make_float4(0.f, 0.f, 0.f, 0.f);
    if (arow_ok) {
      if (bidxg) {
        int k = koff + kt + (akq << 2);
        int l = k >> 6, j = k & 63;
        const float* ap = (l < LLL)
            ? (Av + (size_t)bidxg[arow_g * LLL + l] * 64 + j)
            : (Sg + (size_t)arow_g * 64 + j);
        av = *(const float4*)ap;
      } else {
        av = *(const float4*)(Av + asrc + kt + (akq << 2));
      }
    }
    As[(akq << 2) + 0][arow_l] = av.x;
    As[(akq << 2) + 1][arow_l] = av.y;
    As[(akq << 2) + 2][arow_l] = av.z;
    As[(akq << 2) + 3][arow_l] = av.w;
#pragma unroll
    for (int p = 0; p < WLOADS; ++p) {
      int f = tid + p * 256;
      int krow = f / WQ4, c4 = f % WQ4;
      *(float4*)&Ws[krow][c4 << 2] =
          *(const float4*)(W + (long long)(kt + krow) * ldw + (c4 << 2));
    }
    __syncthreads();
#pragma unroll
    for (int kk = 0; kk < BK; ++kk) {
      float a[TM], b[TN];
      if constexpr (TM % 4 == 0) {
#pragma unroll
        for (int i = 0; i < TM; i += 4)
          *(float4*)&a[i] = *(const float4*)&As[kk][ty * TM + i];
      } else {
#pragma unroll
        for (int i = 0; i < TM; ++i) a[i] = As[kk][ty * TM + i];
      }
      *(float4*)&b[0] = *(const float4*)&Ws[kk][tx * TN];
#pragma unroll
      for (int i = 0; i < TM; ++i)
#pragma unroll
        for (int j = 0; j < TN; ++j)
          acc[i][j] = fmaf(a[i], b[j], acc[i][j]);
    }
    __syncthreads();
  }

#pragma unroll
  for (int i = 0; i < TM; ++i) {
    int r = bm0 + ty * TM + i;
    if (r >= M) continue;
    float4 v = make_float4(acc[i][0], acc[i][1], acc[i][2], acc[i][3]);
    if (biasp != nullptr) {
      v.x += biasp[tx * TN + 0]; v.y += biasp[tx * TN + 1];
      v.z += biasp[tx * TN + 2]; v.w += biasp[tx * TN + 3];
    }
    *(float4*)(Cv + (long long)r * ldc + bn0 + tx * TN) = v;
  }
}

// ---------------------------------------------------------------------------
// Weight fusion stage 1: T1 = wgc1@wgc2, T2 = lin1@wgc2, ta = bgc1@wgc2,
// tb = lin1b@wgc2  (all K=128 dots)
// ---------------------------------------------------------------------------
__global__ __launch_bounds__(256)
void fuse1_k(const float* __restrict__ wgc1, const float* __restrict__ lin1,
             const float* __restrict__ bgc1, const float* __restrict__ lin1b,
             const float* __restrict__ wgc2,
             float* __restrict__ T1, float* __restrict__ T2,
             float* __restrict__ ta, float* __restrict__ tb)
{
  int t = blockIdx.x * 256 + threadIdx.x;
  const float* Arow; float* outp; int n;
  if (t < 32768)      { n = t & 127; Arow = wgc1 + (t >> 7) * 128; outp = T1 + t; }
  else if (t < 65536) { int u = t - 32768; n = u & 127; Arow = lin1 + (u >> 7) * 128; outp = T2 + u; }
  else if (t < 65664) { n = t - 65536; Arow = bgc1;  outp = ta + n; }
  else if (t < 65792) { n = t - 65664; Arow = lin1b; outp = tb + n; }
  else return;
  float s = 0.f;
  for (int k = 0; k < 128; ++k) s = fmaf(Arow[k], wgc2[k * 128 + n], s);
  *outp = s;
}

// ---------------------------------------------------------------------------
// Weight fusion stage 2: Wab[:,0:64] = T1@w2, Wab[:,64:128] = T2@w2,
// bab = [ta@w2 | tb@w2], bc = bgc2@w2
// ---------------------------------------------------------------------------
__global__ __launch_bounds__(256)
void fuse2_k(const float* __restrict__ T1, const float* __restrict__ T2,
             const float* __restrict__ ta, const float* __restrict__ tb,
             const float* __restrict__ bgc2, const float* __restrict__ w2,
             float* __restrict__ Wab, float* __restrict__ bab,
             float* __restrict__ bcv)
{
  int t = blockIdx.x * 256 + threadIdx.x;
  const float* Arow; float* outp; int j;
  if (t < 32768) {
    int c = t & 127; j = c & 63;
    Arow = (c < 64 ? T1 : T2) + (t >> 7) * 128;
    outp = Wab + t;
  } else if (t < 32896) {
    int c = t - 32768; j = c & 63; Arow = (c < 64) ? ta : tb; outp = bab + c;
  } else if (t < 32960) {
    j = t - 32896; Arow = bgc2; outp = bcv + j;
  } else return;
  float s = 0.f;
  for (int k = 0; k < 128; ++k) s = fmaf(Arow[k], w2[k * 64 + j], s);
  *outp = s;
}

// ---------------------------------------------------------------------------
// CSR build: fine histogram -> 3-pass exclusive scan (-> rp), then
// two-level placement carrying (dst,src,w) sequentially so the spmms read a
// packed (src,w) array in CSR order with zero random metadata gathers.
// ---------------------------------------------------------------------------
__global__ __launch_bounds__(256)
void hist_k(const int* __restrict__ dst, int* __restrict__ cur)
{
  int e = blockIdx.x * 256 + threadIdx.x;
  if (e < EE) atomicAdd(&cur[dst[e]], 1);
}

__global__ __launch_bounds__(256)
void scan1_k(const int* __restrict__ cnt, int* __restrict__ rp1,
             int* __restrict__ part, int n)
{
  __shared__ int s[256];
  int t = threadIdx.x;
  int base = blockIdx.x * 1024 + t * 4;
  int a0 = (base + 0 < n) ? cnt[base + 0] : 0;
  int a1 = (base + 1 < n) ? cnt[base + 1] : 0;
  int a2 = (base + 2 < n) ? cnt[base + 2] : 0;
  int a3 = (base + 3 < n) ? cnt[base + 3] : 0;
  s[t] = a0 + a1 + a2 + a3;
  __syncthreads();
  for (int off = 1; off < 256; off <<= 1) {
    int v = (t >= off) ? s[t - off] : 0;
    __syncthreads();
    s[t] += v;
    __syncthreads();
  }
  int pre = t ? s[t - 1] : 0;
  int r0 = pre + a0, r1 = r0 + a1, r2 = r1 + a2, r3 = r2 + a3;
  if (base + 0 < n) rp1[base + 0] = r0;
  if (base + 1 < n) rp1[base + 1] = r1;
  if (base + 2 < n) rp1[base + 2] = r2;
  if (base + 3 < n) rp1[base + 3] = r3;
  if (t == 255) part[blockIdx.x] = s[255];
}

__global__ __launch_bounds__(256)
void scan2_k(int* __restrict__ part, int nb)
{
  __shared__ int s[256];
  int t = threadIdx.x;
  int v = (t < nb) ? part[t] : 0;
  s[t] = v;
  __syncthreads();
  for (int off = 1; off < 256; off <<= 1) {
    int u = (t >= off) ? s[t - off] : 0;
    __syncthreads();
    s[t] += u;
    __syncthreads();
  }
  if (t < nb) part[t] = s[t] - v;     // exclusive
}

__global__ __launch_bounds__(256)
void scan3_k(int* __restrict__ rp, const int* __restrict__ part, int n)
{
  int i = blockIdx.x * 256 + threadIdx.x;
  if (i == 0) rp[0] = 0;
  if (i < n) rp[1 + i] += part[i >> 10];
}

// gcur[c] = rp[c*512]  (coarse bucket write cursors)
__global__ __launch_bounds__(256)
void initcur_k(const int* __restrict__ rp, int* __restrict__ gcur)
{
  int t = threadIdx.x;
  if (t < NB) gcur[t] = rp[t << BSH];
}

// Level 1: bin edges into coarse buckets, streaming (dst,src,w) coalesced.
__global__ __launch_bounds__(256)
void bin_k(const int* __restrict__ edst, const int* __restrict__ esrc,
           const float* __restrict__ ew, int* __restrict__ gcur,
           int4* __restrict__ ebd)
{
  __shared__ int lcnt[NB];
  __shared__ int lbase[NB];
  const int tid = threadIdx.x;
  const int e0 = blockIdx.x * EPB;
  const int e1 = min(EE, e0 + EPB);
  for (int i = tid; i < NB; i += 256) lcnt[i] = 0;
  __syncthreads();
  int dv[16], sv[16], wv[16];
#pragma unroll
  for (int u = 0; u < 16; ++u) {
    int e = e0 + u * 256 + tid;
    if (e < e1) {
      dv[u] = edst[e];
      sv[u] = esrc[e];
      wv[u] = __float_as_int(ew[e]);
      atomicAdd(&lcnt[dv[u] >> BSH], 1);
    } else dv[u] = -1;
  }
  __syncthreads();
  for (int i = tid; i < NB; i += 256) {
    lbase[i] = atomicAdd(&gcur[i], lcnt[i]);
    lcnt[i] = 0;
  }
  __syncthreads();
#pragma unroll
  for (int u = 0; u < 16; ++u) {
    if (dv[u] >= 0) {
      int c = dv[u] >> BSH;
      int k = atomicAdd(&lcnt[c], 1);
      int4 p; p.x = dv[u]; p.y = sv[u]; p.z = wv[u]; p.w = 0;
      ebd[lbase[c] + k] = p;
    }
  }
}

// Level 2: one block per bucket; write packed (src,w) into CSR slots.
// sw writes stay inside a ~16KB L2-resident window -> no amplification.
__global__ __launch_bounds__(256)
void sort_k(const int4* __restrict__ ebd, const int* __restrict__ rp,
            int2* __restrict__ sw)
{
  __shared__ int rpl[512];
  __shared__ int lcur[512];
  const int c = blockIdx.x;
  const int n0 = c << BSH;
  const int n1 = min(NN, n0 + 512);
  const int nn = n1 - n0;
  const int tid = threadIdx.x;
  for (int i = tid; i < nn; i += 256) { rpl[i] = rp[n0 + i]; lcur[i] = 0; }
  __syncthreads();
  const int b0 = rp[n0];
  const int b1 = rp[n1];
  for (int i = b0 + tid; i < b1; i += 256) {
    int4 p = ebd[i];
    int li = p.x - n0;
    int k = atomicAdd(&lcur[li], 1);
    int2 q; q.x = p.y; q.y = p.z;
    sw[rpl[li] + k] = q;
  }
}

// ---------------------------------------------------------------------------
// CSR spmm on 64-wide f32 rows (src row stride GLD): one wave per dst node,
// lane owns one column. Packed sw=(src,wbits) read wave-uniform (broadcast);
// int fixed-point accumulate -> bit-deterministic.
//  MODE 1: out = acc*INVS + bias[lane]
//  MODE 2: out = n[d]*P[d,lane] + (1-n[d])*acc*INVS + bias[lane]
// ---------------------------------------------------------------------------
template<int MODE, int GLD>
__global__ __launch_bounds__(256)
void spmm64(const int* __restrict__ rp, const int2* __restrict__ sw,
            const float* __restrict__ Gf, float* __restrict__ xout,
            const float* __restrict__ bias, const float* __restrict__ npar,
            const float* __restrict__ QP)
{
  int widx = blockIdx.x * 4 + (threadIdx.x >> 6);
  if (widx >= NN) return;
  int lane = threadIdx.x & 63;
  int e0 = rp[widx], e1 = rp[widx + 1];
  int acc = 0;
  int j = e0;
  for (; j + 8 <= e1; j += 8) {
    float gv[8], wv[8];
#pragma unroll
    for (int u = 0; u < 8; ++u) {
      int2 q = sw[j + u];                       // wave-uniform -> broadcast
      wv[u] = __int_as_float(q.y);
      gv[u] = Gf[(size_t)q.x * GLD + lane];
    }
#pragma unroll
    for (int u = 0; u < 8; ++u)
      acc += __float2int_rn(gv[u] * wv[u] * FIXS);
  }
  for (; j < e1; ++j) {
    int2 q = sw[j];
    acc += __float2int_rn(Gf[(size_t)q.x * GLD + lane] *
                          __int_as_float(q.y) * FIXS);
  }
  float v = (float)acc * INVS;
  if (MODE == 1) {
    xout[(size_t)widx * 64 + lane] = v + bias[lane];
  } else {
    float nv = npar[widx];
    float p = QP[(size_t)widx * 128 + 64 + lane];
    xout[(size_t)widx * 64 + lane] = nv * p + (1.f - nv) * v + bias[lane];
  }
}

// ---------------------------------------------------------------------------
// S[b,:] = sum_l Z[bidx[b,l],:] - 49*b2   (Z rows already carry +b2 each)
// ---------------------------------------------------------------------------
__global__ __launch_bounds__(256)
void sumS_k(const float* __restrict__ Z, const int* __restrict__ bidx,
            const float* __restrict__ b2, float* __restrict__ S)
{
  int wv = threadIdx.x >> 6;
  int lane = threadIdx.x & 63;
  int b = blockIdx.x * 4 + wv;
  if (b >= BBB) return;
  const int* bi = bidx + (size_t)b * LLL;
  float s = 0.f;
  for (int l = 0; l < LLL; ++l)
    s += Z[(size_t)bi[l] * 64 + lane];
  S[(size_t)b * 64 + lane] = s - 49.f * b2[lane];
}

// ---------------------------------------------------------------------------
// sel = P4[0]+P4[1]+P4[2]+P4[3] + l1b  (fixed order -> deterministic)
// ---------------------------------------------------------------------------
__global__ __launch_bounds__(256)
void reduce4_k(const float* __restrict__ P4, const float* __restrict__ l1b,
               float* __restrict__ sel)
{
  int t = blockIdx.x * 256 + threadIdx.x;
  if (t >= BBB * 32) return;
  int r = t >> 5, c4 = t & 31;
  size_t off = (size_t)r * 128 + (c4 << 2);
  const size_t zs = (size_t)BBB * 128;
  float4 s0 = *(const float4*)(P4 + off);
  float4 s1 = *(const float4*)(P4 + zs + off);
  float4 s2 = *(const float4*)(P4 + 2 * zs + off);
  float4 s3 = *(const float4*)(P4 + 3 * zs + off);
  float4 b  = *(const float4*)(l1b + (c4 << 2));
  float4 o;
  o.x = ((s0.x + s1.x) + s2.x) + s3.x + b.x;
  o.y = ((s0.y + s1.y) + s2.y) + s3.y + b.y;
  o.z = ((s0.z + s1.z) + s2.z) + s3.z + b.z;
  o.w = ((s0.w + s1.w) + s2.w) + s3.w + b.w;
  *(float4*)(sel + off) = o;
}

// ---------------------------------------------------------------------------
// Classifier + argmax (first-max tie-break, matches jnp.argmax).
// ---------------------------------------------------------------------------
__global__ __launch_bounds__(256)
void cls_k(const float* __restrict__ sel, const float* __restrict__ Wc,
           const float* __restrict__ bc, float* __restrict__ outIdx)
{
  int wv = threadIdx.x >> 6;
  int lane = threadIdx.x & 63;
  int b = blockIdx.x * 4 + wv;
  if (b >= BBB) return;
  float logit = -1e30f;
  if (lane < NCLS) {
    float s = bc[lane];
    const float* sr = sel + (size_t)b * DD;
    for (int d = 0; d < DD; ++d) s = fmaf(sr[d], Wc[d * NCLS + lane], s);
    logit = s;
  }
  float best = -1e30f; int bi = 0;
  for (int c = 0; c < NCLS; ++c) {
    float v = __shfl(logit, c, 64);
    if (v > best) { best = v; bi = c; }
  }
  if (lane == 0) outIdx[b] = (float)bi;
}

// ---------------------------------------------------------------------------
extern "C" void kernel_launch(void* const* d_in, const int* in_sizes, int n_in,
                              void* d_out, int out_size, void* d_ws, size_t ws_size,
                              hipStream_t stream)
{
  const float* A1    = (const float*)d_in[0];
  const int*   esrc  = (const int*)d_in[1];
  const int*   edst  = (const int*)d_in[2];
  const float* ew    = (const float*)d_in[3];
  const int*   bidx  = (const int*)d_in[4];   // [B,1,L] == [B*L]
  const float* wgc1  = (const float*)d_in[5];
  const float* bgc1  = (const float*)d_in[6];
  const float* wgc2  = (const float*)d_in[7];
  const float* bgc2  = (const float*)d_in[8];
  const float* npar  = (const float*)d_in[9];
  const float* lin1  = (const float*)d_in[10];
  const float* lin1b = (const float*)d_in[11];
  const float* w2    = (const float*)d_in[12];
  const float* b2    = (const float*)d_in[13];
  const float* l1w   = (const float*)d_in[14];
  const float* l1b   = (const float*)d_in[15];
  const float* clsw  = (const float*)d_in[16];
  const float* clsb  = (const float*)d_in[17];

  float* out = (float*)d_out;
  float* sel = out + BBB;

  // workspace layout (peak ~91.9 MB; proven floor from round 1 is 104.67 MB)
  // ebd (25.6 MB) overlaps QP: dead before the QP GEMM launches (stream order).
  uint8_t* ws   = (uint8_t*)d_ws;
  float*   QP   = (float*)(ws);                 // 51.2 MB [N,128]; Z reuses 1st half
  int4*    ebd  = (int4*) (ws);                 // 25.6 MB [E] (d,s,w) - CSR build only
  float*   G    = (float*)(ws + 51200000);      // 25.6 MB [N,64]; P4 reuses it
  float*   Z    = (float*)(ws);                 // 25.6 MB [N,64] (over QP)
  float*   P4   = (float*)(ws + 51200000);      //  8.4 MB 4x[B,128] (over G)
  int2*    sw   = (int2*) (ws + 76800000);      // 12.8 MB packed (src,w) CSR order
  int*     rp   = (int*)  (ws + 89600000);      //  0.4 MB (N+1)
  int*     cur  = (int*)  (ws + 90000016);      //  0.4 MB (hist; reused as gcur)
  int*     part = (int*)  (ws + 90400016);      //  512 B
  float*   S    = (float*)(ws + 90400528);      //  1.0 MB [B,64]
  float*   T1   = (float*)(ws + 91449104);      // 128 KB [256,128]
  float*   T2   = (float*)(ws + 91580176);      // 128 KB
  float*   Wab  = (float*)(ws + 91711248);      // 128 KB [256,128]
  float*   ta   = (float*)(ws + 91842320);      // 512 B
  float*   tb   = (float*)(ws + 91842832);      // 512 B
  float*   bab  = (float*)(ws + 91843344);      // 512 B [128]
  float*   bcv  = (float*)(ws + 91843856);      // 256 B [64]

  dim3 blk(256);

  // ---- weight fusion (2 launches) ----
  hipLaunchKernelGGL(fuse1_k, dim3(257), blk, 0, stream,
      wgc1, lin1, bgc1, lin1b, wgc2, T1, T2, ta, tb);
  hipLaunchKernelGGL(fuse2_k, dim3(129), blk, 0, stream,
      T1, T2, ta, tb, bgc2, w2, Wab, bab, bcv);

  // ---- CSR build ----
  hipMemsetAsync(cur, 0, NN * 4, stream);
  hipLaunchKernelGGL(hist_k, dim3(EE / 256), blk, 0, stream, edst, cur);
  hipLaunchKernelGGL(scan1_k, dim3(98), blk, 0, stream, cur, rp + 1, part, NN);
  hipLaunchKernelGGL(scan2_k, dim3(1), blk, 0, stream, part, 98);
  hipLaunchKernelGGL(scan3_k, dim3(391), blk, 0, stream, rp, part, NN);
  hipLaunchKernelGGL(initcur_k, dim3(1), blk, 0, stream, rp, cur);
  hipLaunchKernelGGL(bin_k, dim3((EE + EPB - 1) / EPB), blk, 0, stream,
      edst, esrc, ew, cur, ebd);
  hipLaunchKernelGGL(sort_k, dim3(NB), blk, 0, stream, ebd, rp, sw);

  // ---- QP = A1 @ Wab + bab  [N,128]  (Q = cols 0..63, P = cols 64..127) ----
  hipLaunchKernelGGL((gemm_f32<64,128,16,8,4>), dim3(1563, 1, 1), blk, 0, stream,
      A1, EMBD, Wab, 128, bab, QP, 128,
      NN, EMBD, EMBD, (const int*)nullptr, (const float*)nullptr);

  // ---- G = n*P + (1-n)*spmm(Q) + bc   (combine fused into spmm epilogue) ----
  hipLaunchKernelGGL((spmm64<2,128>), dim3(NN / 4), blk, 0, stream,
      rp, sw, QP, G, bcv, npar, QP);

  // ---- Z = spmm(G) + b2  [N,64] (overwrites QP's first half) ----
  hipLaunchKernelGGL((spmm64<1,64>), dim3(NN / 4), blk, 0, stream,
      rp, sw, G, Z, b2, (const float*)nullptr, (const float*)nullptr);

  // ---- S[b] = sum_l Z[bidx[b,l]] - 49*b2 ----
  hipLaunchKernelGGL(sumS_k, dim3(BBB / 4), blk, 0, stream, Z, bidx, b2, S);

  // ---- P4[z] = [gather(Z)|S] @ l1w (K-chunk z)  grid (128,2,4) ----
  hipLaunchKernelGGL((gemm_f32<32,64,32,2,4>), dim3(BBB / 32, 2, 4), blk, 0, stream,
      Z, 64, l1w, DD, (const float*)nullptr, P4, DD,
      BBB, (LLL + 1) * 64, 13 * 64, bidx, S);

  // ---- sel = sum_z P4[z] + l1b ----
  hipLaunchKernelGGL(reduce4_k, dim3(BBB * 32 / 256), blk, 0, stream, P4, l1b, sel);

  // ---- argmax(sel @ classifier + bias) -> out[0:B] ----
  hipLaunchKernelGGL(cls_k, dim3(BBB / 4), blk, 0, stream, sel, clsw, clsb, out);
}